// Round 6
// baseline (620.417 us; speedup 1.0000x reference)
//
#include <hip/hip_runtime.h>
#include <hip/hip_bf16.h>

#define S_LEN 2048
#define DMODEL 512
#define NHEAD 8
#define DKH 64
#define FFDIM 2048
#define BATCH 2
#define NROWS (BATCH * S_LEN)  // 4096

using bf16 = __hip_bfloat16;
typedef __bf16 bf16x8 __attribute__((ext_vector_type(8)));
typedef float floatx4 __attribute__((ext_vector_type(4)));
typedef float floatx16 __attribute__((ext_vector_type(16)));

// fp32 -> bf16 round-to-nearest-even, branch-free (scalar path, cvt kernel)
__device__ inline unsigned short f2bf_bits(float f) {
    union { float f; unsigned u; } c; c.f = f;
    return (unsigned short)((c.u + 0x7FFFu + ((c.u >> 16) & 1u)) >> 16);
}
__device__ inline unsigned pack2bf(float a, float b) {
    return (unsigned)f2bf_bits(a) | ((unsigned)f2bf_bits(b) << 16);
}
// packed conversion (v_cvt_pk_bf16_f32 on gfx950)
__device__ inline unsigned pk2(float a, float b) {
    float2 f; f.x = a; f.y = b;
    __hip_bfloat162 h = __float22bfloat162_rn(f);
    return *(unsigned*)&h;
}

// async global->LDS, 16 bytes/lane. LDS dest is wave-uniform base + lane*16.
__device__ __forceinline__ void gload_lds16(const bf16* g, bf16* l) {
    __builtin_amdgcn_global_load_lds(
        (const __attribute__((address_space(1))) void*)(const void*)g,
        (__attribute__((address_space(3))) void*)(void*)l, 16, 0, 0);
}

// ---------------------------------------------------------------------------
// fp32 -> bf16 bulk convert, up to 12 segments in one dispatch.
// ---------------------------------------------------------------------------
struct CvtSeg { const float* s; bf16* d; int n4; };
struct CvtDesc { CvtSeg seg[12]; };

__launch_bounds__(256)
__global__ void cvt_f32_bf16(CvtDesc desc) {
    const CvtSeg sg = desc.seg[blockIdx.y];
    const int stride = gridDim.x * 256;
    for (int i = blockIdx.x * 256 + threadIdx.x; i < sg.n4; i += stride) {
        const float4 v = ((const float4*)sg.s)[i];
        uint2 o;
        o.x = pack2bf(v.x, v.y);
        o.y = pack2bf(v.z, v.w);
        ((uint2*)sg.d)[i] = o;
    }
}

// ---------------------------------------------------------------------------
// GEMM v2: C[M,N] = A[M,K] @ W[N,K]^T, BK=64 as two BK=32 panels. Epilogue
// routes 2^shift-wide column slabs to up to 3 outputs with per-slab bias/
// scale; A2 (if set) replaces A for slabs >= a2slab (fused cross Q|K|V with
// different activation sources). 4 waves (2x2), one barrier pair per 64-k.
// ---------------------------------------------------------------------------
struct Epi {
    bf16*  outB[3];
    float* outF[3];
    const float* bias[3];
    float scale[3];
    const bf16* A2;   // alternate A source for slabs >= a2slab (or null)
    int a2slab;
    int shift;        // log2(slab width): 9 for 512-wide outputs, 11 for FFN1
    int relu;
};

template <int BM, int BN>
__launch_bounds__(256)
__global__ void gemm2(const bf16* __restrict__ A, const bf16* __restrict__ W,
                      Epi epi, int K)
{
    constexpr int WR = BM / 32;
    constexpr int WC = BN / 32;
    constexpr int SA = BM / 16;          // A gload segments per panel
    constexpr int SB = BN / 16;
    constexpr int NG = 2 * (SA + SB);    // gloads per iter (1KB each)

    __shared__ alignas(16) bf16 As[2][BM][32];
    __shared__ alignas(16) bf16 Bs[2][BN][32];

    const int t = threadIdx.x;
    const int w = t >> 6;
    const int lane = t & 63;
    const int r16 = lane & 15;
    const int quad = lane >> 4;
    const int wm = w >> 1, wn = w & 1;
    const int m0 = blockIdx.x * BM;
    const int n0 = blockIdx.y * BN;

    const bf16* Ause = (epi.A2 && ((n0 >> epi.shift) >= epi.a2slab)) ? epi.A2 : A;

    floatx4 acc[WR][WC];
#pragma unroll
    for (int i = 0; i < WR; i++)
#pragma unroll
        for (int j = 0; j < WC; j++)
#pragma unroll
            for (int e = 0; e < 4; e++) acc[i][j][e] = 0.0f;

    const int grow = lane >> 2;        // row within 16-row gload segment
    const int gcol = (lane & 3) * 8;   // k-offset within 32-panel

    for (int k0 = 0; k0 < K; k0 += 64) {
        __syncthreads();
#pragma unroll
        for (int s = 0; s < NG; s += 4) {
            int sg = s + w;
            int p = 0;
            if (sg >= SA + SB) { p = 1; sg -= SA + SB; }
            const bf16* src;
            bf16* dst;
            if (sg < SA) {
                src = Ause + (size_t)(m0 + sg * 16 + grow) * K + k0 + 32 * p + gcol;
                dst = &As[p][sg * 16][0] + lane * 8;
            } else {
                const int sb = sg - SA;
                src = W + (size_t)(n0 + sb * 16 + grow) * K + k0 + 32 * p + gcol;
                dst = &Bs[p][sb * 16][0] + lane * 8;
            }
            gload_lds16(src, dst);
        }
        __syncthreads();

        bf16x8 af[2][WR], bfr[2][WC];
#pragma unroll
        for (int p = 0; p < 2; p++) {
#pragma unroll
            for (int i = 0; i < WR; i++)
                af[p][i] = *(const bf16x8*)&As[p][wm * (BM / 2) + 16 * i + r16][quad * 8];
#pragma unroll
            for (int j = 0; j < WC; j++)
                bfr[p][j] = *(const bf16x8*)&Bs[p][wn * (BN / 2) + 16 * j + r16][quad * 8];
        }
#pragma unroll
        for (int p = 0; p < 2; p++)
#pragma unroll
            for (int i = 0; i < WR; i++)
#pragma unroll
                for (int j = 0; j < WC; j++)
                    acc[i][j] = __builtin_amdgcn_mfma_f32_16x16x32_bf16(af[p][i], bfr[p][j], acc[i][j], 0, 0, 0);
    }

    const int mask = (1 << epi.shift) - 1;
#pragma unroll
    for (int j = 0; j < WC; j++) {
        const int colb = n0 + wn * (BN / 2) + 16 * j;
        const int sel = __builtin_amdgcn_readfirstlane(colb >> epi.shift);
        const int lcol = (colb & mask) + r16;
        const int ldw = mask + 1;
        const float bv = epi.bias[sel] ? epi.bias[sel][lcol] : 0.0f;
        const float sc = epi.scale[sel];
        bf16* ob = epi.outB[sel];
        float* of = epi.outF[sel];
#pragma unroll
        for (int i = 0; i < WR; i++) {
            const int rowb = m0 + wm * (BM / 2) + 16 * i + 4 * quad;
#pragma unroll
            for (int e = 0; e < 4; e++) {
                float v = (acc[i][j][e] + bv) * sc;
                if (epi.relu) v = fmaxf(v, 0.0f);
                const size_t idx = (size_t)(rowb + e) * ldw + lcol;
                if (of) of[idx] = v;
                if (ob) ob[idx] = __float2bfloat16(v);
            }
        }
    }
}

// ---------------------------------------------------------------------------
// Flash attention, 32x32x16 MFMA — round-15: OCCUPANCY.
// Post-mortem of r0-r5: attn pinned at 65.6us across 5 structures; the
// invariant is ~8 waves/CU (2/SIMD): r0 was grid-limited (512 blocks x 4
// waves), r3/r5 doubled waves/block AND LDS (2 blocks -> 1-2/CU). With 2
// waves/SIMD the per-chunk latency chain (~2.5k cyc) can't overlap ->
// latency-bound, all pipes idle (MfmaUtil 10 / VALU 28 / HBM 7.6 / Occ 20).
// This round: QBLK=32, 4 waves/block, grid 64x16=1024 blocks, 36.9KB LDS
// -> 4 blocks/CU co-resident = 16 waves/CU = 4 waves/SIMD (2x), and ZERO
// barriers in the K-loop (per-wave V half-plane [64][36] staged 32 keys at
// a time + per-wave Ps plane; per-wave DS ops are in-order so the plane is
// reused across halves/chunks without sync). V staging remapped to 100%
// cache-line utilization (8 full 128B rows per instr). K fragments from
// global (r0/r3 behavior — proven cost-neutral). kf prefetch issued after
// softmax so peak VGPR stays under the 128 cap of launch_bounds(256,4).
// Merge: 3-barrier tree across the 4 waves, scratch overlays dead LDS.
// ---------------------------------------------------------------------------
#define PST 72    // Ps row stride (bf16)
#define PSTH 36   // V half-plane row stride (bf16): 32 + 4

__launch_bounds__(256, 4)
__global__ void attn_mfma(const bf16* __restrict__ Qh, const bf16* __restrict__ Kh,
                          const bf16* __restrict__ Vh,
                          float* __restrict__ outF, bf16* __restrict__ outB,
                          int causal)
{
    // [0,18432):     Vt[4][64][PSTH] bf16 (per-wave V half-planes, d-major)
    // [18432,36864): Ps[4][32][PST]  bf16 (per-wave P planes)
    // after loop: Msh[2][64][34] fp32 (17408 B) overlays [0,18432)+
    __shared__ alignas(16) char smem[36864];
    typedef bf16 (*VtT)[64][PSTH];
    typedef bf16 (*PsT)[32][PST];
    VtT Vt = (VtT)smem;
    PsT Ps = (PsT)(smem + 18432);
    typedef float (*MshT)[64][34];
    MshT Msh = (MshT)smem;

    const int t = threadIdx.x;        // 0..255
    const int w = t >> 6;             // 0..3 (= key-split index)
    const int lane = t & 63;
    const int c32 = lane & 31;
    const int hi = lane >> 5;
    const int bh = blockIdx.y;
    const int b = bh >> 3, h = bh & 7;
    const int q0 = blockIdx.x * 32;
    const size_t rowbase = (size_t)b * S_LEN;
    const int hoff = h * DKH;

    // Q fragments (same 32 q-rows for all 4 waves)
    bf16x8 qf[4];
    {
        const bf16* qp = Qh + (rowbase + q0 + c32) * DMODEL + hoff + 8 * hi;
#pragma unroll
        for (int tt = 0; tt < 4; tt++) qf[tt] = *(const bf16x8*)(qp + 16 * tt);
    }

    floatx16 o0, o1;
#pragma unroll
    for (int e = 0; e < 16; e++) { o0[e] = 0.0f; o1[e] = 0.0f; }
    float m = -3e38f, l = 0.0f;

    // V staging lane map: 8 lanes of d-slices x 8 row-quads -> 100% line use
    const int vq = lane & 7;          // row-quad: rows 4vq..4vq+3 of the half
    const int vd = (lane >> 3) * 8;   // d-slice 0..56

    const int nchunk = causal ? (q0 / 64 + 1) : (S_LEN / 64);

    // K fragments for this wave's first chunk
    bf16x8 kf0[4], kf1[4];
    if (w < nchunk) {
        const bf16* kp = Kh + (rowbase + w * 64 + c32) * DMODEL + hoff + 8 * hi;
#pragma unroll
        for (int tt = 0; tt < 4; tt++) {
            kf0[tt] = *(const bf16x8*)(kp + 16 * tt);
            kf1[tt] = *(const bf16x8*)(kp + (size_t)32 * DMODEL + 16 * tt);
        }
    }

    for (int ch = w; ch < nchunk; ch += 4) {
        const int kb = ch * 64;

        // ---- QK^T ----
        floatx16 s0, s1;
#pragma unroll
        for (int e = 0; e < 16; e++) { s0[e] = 0.0f; s1[e] = 0.0f; }
        __builtin_amdgcn_s_setprio(1);
#pragma unroll
        for (int tt = 0; tt < 4; tt++) {
            s0 = __builtin_amdgcn_mfma_f32_32x32x16_bf16(kf0[tt], qf[tt], s0, 0, 0, 0);
            s1 = __builtin_amdgcn_mfma_f32_32x32x16_bf16(kf1[tt], qf[tt], s1, 0, 0, 0);
        }
        __builtin_amdgcn_s_setprio(0);

        // ---- issue V half0 loads (rows kb..kb+31), coalesced 128B rows ----
        const bf16* vb0 = Vh + (rowbase + kb + 4 * vq) * DMODEL + hoff + vd;
        uint4 va0 = *(const uint4*)(vb0);
        uint4 va1 = *(const uint4*)(vb0 + DMODEL);
        uint4 va2 = *(const uint4*)(vb0 + 2 * DMODEL);
        uint4 va3 = *(const uint4*)(vb0 + 3 * DMODEL);

        // ---- causal mask (diagonal chunk only) ----
        if (causal && ch == nchunk - 1) {
            const int qq = q0 + c32;
#pragma unroll
            for (int r = 0; r < 16; r++) {
                const int kl = kb + (r & 3) + 8 * (r >> 2) + 4 * hi;
                if (kl > qq) s0[r] = -3e38f;
                if (kl + 32 > qq) s1[r] = -3e38f;
            }
        }

        // ---- online softmax (exp2 domain, defer-max) ----
        float mc = -3e38f;
#pragma unroll
        for (int r = 0; r < 16; r++) mc = fmaxf(mc, fmaxf(s0[r], s1[r]));
        mc = fmaxf(mc, __shfl_xor(mc, 32, 64));

        float alpha = 1.0f;
        if (!__all(mc <= m + 8.0f)) {
            const float mold = m;
            m = fmaxf(m, mc);
            alpha = __builtin_amdgcn_exp2f(mold - m);
#pragma unroll
            for (int r = 0; r < 16; r++) {
                const float a = __shfl(alpha, (r & 3) + 8 * (r >> 2) + 4 * hi, 64);
                o0[r] *= a; o1[r] *= a;
            }
        }

        float lc = 0.0f;
#pragma unroll
        for (int g = 0; g < 4; g++) {
            float p0 = __builtin_amdgcn_exp2f(s0[4 * g + 0] - m);
            float p1 = __builtin_amdgcn_exp2f(s0[4 * g + 1] - m);
            float p2 = __builtin_amdgcn_exp2f(s0[4 * g + 2] - m);
            float p3 = __builtin_amdgcn_exp2f(s0[4 * g + 3] - m);
            lc += (p0 + p1) + (p2 + p3);
            uint2 pw; pw.x = pk2(p0, p1); pw.y = pk2(p2, p3);
            *(uint2*)&Ps[w][c32][8 * g + 4 * hi] = pw;
            p0 = __builtin_amdgcn_exp2f(s1[4 * g + 0] - m);
            p1 = __builtin_amdgcn_exp2f(s1[4 * g + 1] - m);
            p2 = __builtin_amdgcn_exp2f(s1[4 * g + 2] - m);
            p3 = __builtin_amdgcn_exp2f(s1[4 * g + 3] - m);
            lc += (p0 + p1) + (p2 + p3);
            uint2 pw1; pw1.x = pk2(p0, p1); pw1.y = pk2(p2, p3);
            *(uint2*)&Ps[w][c32][32 + 8 * g + 4 * hi] = pw1;
        }
        lc += __shfl_xor(lc, 32, 64);
        l = l * alpha + lc;

        // ---- prefetch next chunk's K fragments (hidden under PV) ----
        if (ch + 4 < nchunk) {
            const bf16* kp = Kh + (rowbase + (ch + 4) * 64 + c32) * DMODEL + hoff + 8 * hi;
#pragma unroll
            for (int tt = 0; tt < 4; tt++) {
                kf0[tt] = *(const bf16x8*)(kp + 16 * tt);
                kf1[tt] = *(const bf16x8*)(kp + (size_t)32 * DMODEL + 16 * tt);
            }
        }

        // ---- write V half0 transposed into per-wave plane ----
        {
            union { uint4 u; unsigned short s[8]; } r0, r1, r2, r3;
            r0.u = va0; r1.u = va1; r2.u = va2; r3.u = va3;
#pragma unroll
            for (int j = 0; j < 8; j++) {
                ushort4 pk = { r0.s[j], r1.s[j], r2.s[j], r3.s[j] };
                *(ushort4*)&Vt[w][vd + j][4 * vq] = pk;
            }
        }

        // ---- issue V half1 loads (rows kb+32..kb+63) ----
        const bf16* vb1 = Vh + (rowbase + kb + 32 + 4 * vq) * DMODEL + hoff + vd;
        uint4 vc0 = *(const uint4*)(vb1);
        uint4 vc1 = *(const uint4*)(vb1 + DMODEL);
        uint4 vc2 = *(const uint4*)(vb1 + 2 * DMODEL);
        uint4 vc3 = *(const uint4*)(vb1 + 3 * DMODEL);

        // ---- PV half0 (keys kb..kb+31): pf tiles 0,1 ----
        __builtin_amdgcn_s_setprio(1);
#pragma unroll
        for (int tt = 0; tt < 2; tt++) {
            const bf16x8 pf = *(const bf16x8*)&Ps[w][c32][16 * tt + 8 * hi];
            const bf16x8 v0 = *(const bf16x8*)&Vt[w][c32][16 * tt + 8 * hi];
            const bf16x8 v1 = *(const bf16x8*)&Vt[w][32 + c32][16 * tt + 8 * hi];
            o0 = __builtin_amdgcn_mfma_f32_32x32x16_bf16(pf, v0, o0, 0, 0, 0);
            o1 = __builtin_amdgcn_mfma_f32_32x32x16_bf16(pf, v1, o1, 0, 0, 0);
        }
        __builtin_amdgcn_s_setprio(0);

        // ---- write V half1 (per-wave DS is in-order: reads above complete
        //      before these writes land) ----
        {
            union { uint4 u; unsigned short s[8]; } r0, r1, r2, r3;
            r0.u = vc0; r1.u = vc1; r2.u = vc2; r3.u = vc3;
#pragma unroll
            for (int j = 0; j < 8; j++) {
                ushort4 pk = { r0.s[j], r1.s[j], r2.s[j], r3.s[j] };
                *(ushort4*)&Vt[w][vd + j][4 * vq] = pk;
            }
        }

        // ---- PV half1 (keys kb+32..kb+63): pf tiles 2,3 ----
        __builtin_amdgcn_s_setprio(1);
#pragma unroll
        for (int tt = 2; tt < 4; tt++) {
            const bf16x8 pf = *(const bf16x8*)&Ps[w][c32][16 * tt + 8 * hi];
            const bf16x8 v0 = *(const bf16x8*)&Vt[w][c32][16 * (tt - 2) + 8 * hi];
            const bf16x8 v1 = *(const bf16x8*)&Vt[w][32 + c32][16 * (tt - 2) + 8 * hi];
            o0 = __builtin_amdgcn_mfma_f32_32x32x16_bf16(pf, v0, o0, 0, 0, 0);
            o1 = __builtin_amdgcn_mfma_f32_32x32x16_bf16(pf, v1, o1, 0, 0, 0);
        }
        __builtin_amdgcn_s_setprio(0);
    }

    // ---- 4-way split-KV tree merge across waves (overlay dead LDS) ----
    __syncthreads();   // all loop DS ops drained -> safe to overlay
    if (w & 1) {       // waves 1,3 -> slots 0,1
        float* dst = &Msh[w >> 1][lane][0];
        dst[0] = m; dst[1] = l;
#pragma unroll
        for (int r = 0; r < 16; r++) { dst[2 + r] = o0[r]; dst[18 + r] = o1[r]; }
    }
    __syncthreads();
    if ((w & 1) == 0) {   // waves 0,2 combine (un-normalized)
        const float* src = &Msh[w >> 1][lane][0];
        const float m_b = src[0], l_b = src[1];
        const float mt = fmaxf(m, m_b);
        const float sA = __builtin_amdgcn_exp2f(m - mt);
        const float sB = __builtin_amdgcn_exp2f(m_b - mt);
        l = l * sA + l_b * sB;
        m = mt;
#pragma unroll
        for (int r = 0; r < 16; r++) {
            const int ql = (r & 3) + 8 * (r >> 2) + 4 * hi;
            const float sAr = __shfl(sA, ql, 64);
            const float sBr = __shfl(sB, ql, 64);
            o0[r] = o0[r] * sAr + src[2 + r] * sBr;
            o1[r] = o1[r] * sAr + src[18 + r] * sBr;
        }
        if (w == 2) {     // wave2 re-publishes its combined state to slot 1
            float* dst = &Msh[1][lane][0];
            dst[0] = m; dst[1] = l;
#pragma unroll
            for (int r = 0; r < 16; r++) { dst[2 + r] = o0[r]; dst[18 + r] = o1[r]; }
        }
    }
    __syncthreads();
    if (w == 0) {
        const float* src = &Msh[1][lane][0];
        const float m_b = src[0], l_b = src[1];
        const float mt = fmaxf(m, m_b);
        const float sA = __builtin_amdgcn_exp2f(m - mt);
        const float sB = __builtin_amdgcn_exp2f(m_b - mt);
        const float lt = l * sA + l_b * sB;
#pragma unroll
        for (int r = 0; r < 16; r++) {
            const int ql = (r & 3) + 8 * (r >> 2) + 4 * hi;
            const float sAr = __shfl(sA, ql, 64);
            const float sBr = __shfl(sB, ql, 64);
            const float li = 1.0f / __shfl(lt, ql, 64);
            const float v0 = (o0[r] * sAr + src[2 + r] * sBr) * li;
            const float v1 = (o1[r] * sAr + src[18 + r] * sBr) * li;
            const size_t idx = (rowbase + q0 + ql) * DMODEL + hoff + c32;
            if (outF) { outF[idx] = v0; outF[idx + 32] = v1; }
            if (outB) { outB[idx] = __float2bfloat16(v0); outB[idx + 32] = __float2bfloat16(v1); }
        }
    }
}

// ---------------------------------------------------------------------------
// Fused residual + LayerNorm over D=512. One WG (256 thr) per row.
// ---------------------------------------------------------------------------
__launch_bounds__(256)
__global__ void ln_kernel(const float* __restrict__ xmain,
                          const float* __restrict__ resF, const bf16* __restrict__ resB,
                          const float* __restrict__ g, const float* __restrict__ bb,
                          float* __restrict__ outF, bf16* __restrict__ outB)
{
    const int row = blockIdx.x;
    const int t = threadIdx.x;
    const size_t base = (size_t)row * DMODEL;

    float x0 = xmain[base + t];
    float x1 = xmain[base + t + 256];
    if (resF) { x0 += resF[base + t]; x1 += resF[base + t + 256]; }
    if (resB) { x0 += __bfloat162float(resB[base + t]); x1 += __bfloat162float(resB[base + t + 256]); }

    __shared__ float sred[4];
    float s = x0 + x1;
#pragma unroll
    for (int off = 32; off > 0; off >>= 1) s += __shfl_down(s, off);
    if ((t & 63) == 0) sred[t >> 6] = s;
    __syncthreads();
    const float mu = (sred[0] + sred[1] + sred[2] + sred[3]) * (1.0f / DMODEL);

    const float d0 = x0 - mu, d1 = x1 - mu;
    float sv = d0 * d0 + d1 * d1;
#pragma unroll
    for (int off = 32; off > 0; off >>= 1) sv += __shfl_down(sv, off);
    __syncthreads();
    if ((t & 63) == 0) sred[t >> 6] = sv;
    __syncthreads();
    const float var = (sred[0] + sred[1] + sred[2] + sred[3]) * (1.0f / DMODEL);
    const float rstd = rsqrtf(var + 1e-5f);

    const float y0 = d0 * rstd * g[t] + bb[t];
    const float y1 = d1 * rstd * g[t + 256] + bb[t + 256];
    if (outF) { outF[base + t] = y0; outF[base + t + 256] = y1; }
    if (outB) { outB[base + t] = __float2bfloat16(y0); outB[base + t + 256] = __float2bfloat16(y1); }
}

// ---------------------------------------------------------------------------
// Workspace layout (55.5 MB) — see round 5 comment.
// ---------------------------------------------------------------------------
extern "C" void kernel_launch(void* const* d_in, const int* in_sizes, int n_in,
                              void* d_out, int out_size, void* d_ws, size_t ws_size,
                              hipStream_t stream)
{
    const float* x_q       = (const float*)d_in[0];
    const float* x1        = (const float*)d_in[1];
    const float* x2        = (const float*)d_in[2];
    const float* sa_wq     = (const float*)d_in[3];
    const float* sa_bq     = (const float*)d_in[4];
    const float* sa_wk     = (const float*)d_in[5];
    const float* sa_bk     = (const float*)d_in[6];
    const float* sa_wv     = (const float*)d_in[7];
    const float* sa_bv     = (const float*)d_in[8];
    const float* ln1_g     = (const float*)d_in[9];
    const float* ln1_b     = (const float*)d_in[10];
    const float* mha_in_w  = (const float*)d_in[11];
    const float* mha_in_b  = (const float*)d_in[12];
    const float* mha_out_w = (const float*)d_in[13];
    const float* mha_out_b = (const float*)d_in[14];
    const float* ln2_g     = (const float*)d_in[15];
    const float* ln2_b     = (const float*)d_in[16];
    const float* ffn_w1    = (const float*)d_in[17];
    const float* ffn_b1    = (const float*)d_in[18];
    const float* ffn_w2    = (const float*)d_in[19];
    const float* ffn_b2    = (const float*)d_in[20];
    const float* ln3_g     = (const float*)d_in[21];
    const float* ln3_b     = (const float*)d_in[22];

    char* ws = (char*)d_ws;
    const size_t MB = 1024 * 1024;
    const size_t KB = 1024;
    bf16*  q16  = (bf16*)(ws + 0 * MB);
    bf16*  k16  = (bf16*)(ws + 4 * MB);
    bf16*  v16  = (bf16*)(ws + 8 * MB);
    bf16*  a16  = (bf16*)(ws + 12 * MB);
    float* tmp  = (float*)(ws + 16 * MB);
    bf16*  y16  = (bf16*)(ws + 24 * MB);
    bf16*  ya16 = (bf16*)(ws + 28 * MB);
    bf16*  ya2  = (bf16*)(ws + 32 * MB);
    bf16*  xq16 = (bf16*)(ws + 36 * MB);
    bf16*  x116 = (bf16*)(ws + 40 * MB);
    bf16*  x216 = (bf16*)(ws + 44 * MB);
    bf16*  w_sa_qkv = (bf16*)(ws + 48 * MB);            // 1.5 MB (3D x D contig)
    bf16*  w_in   = (bf16*)(ws + 49 * MB + 512 * KB);   // 1.5 MB
    bf16*  w_out  = (bf16*)(ws + 51 * MB);              // 0.5 MB
    bf16*  w_f1   = (bf16*)(ws + 51 * MB + 512 * KB);   // 2 MB
    bf16*  w_f2   = (bf16*)(ws + 53 * MB + 512 * KB);   // 2 MB
    bf16*  h16    = (bf16*)(ws + 0 * MB);               // aliases q..a (dead by FFN)

    const int DD = DMODEL * DMODEL;
    CvtDesc cd;
    cd.seg[0]  = { x_q,       xq16,        (NROWS * DMODEL) / 4 };
    cd.seg[1]  = { x1,        x116,        (NROWS * DMODEL) / 4 };
    cd.seg[2]  = { x2,        x216,        (NROWS * DMODEL) / 4 };
    cd.seg[3]  = { sa_wq,     w_sa_qkv,           DD / 4 };
    cd.seg[4]  = { sa_wk,     w_sa_qkv + DD,      DD / 4 };
    cd.seg[5]  = { sa_wv,     w_sa_qkv + 2 * DD,  DD / 4 };
    cd.seg[6]  = { mha_in_w,  w_in,   3 * DD / 4 };
    cd.seg[7]  = { mha_out_w, w_out,  DD / 4 };
    cd.seg[8]  = { ffn_w1,    w_f1,   (FFDIM * DMODEL) / 4 };
    cd.seg[9]  = { ffn_w2,    w_f2,   (FFDIM * DMODEL) / 4 };
    cd.seg[10] = { x_q,       xq16,   0 };
    cd.seg[11] = { x_q,       xq16,   0 };
    cvt_f32_bf16<<<dim3(64, 10), 256, 0, stream>>>(cd);

    const dim3 blk(256);
    const dim3 ablk(256);
    const dim3 agrid(S_LEN / 32, BATCH * NHEAD);   // (64,16) = 1024 blocks

    // softmax runs in exp2 domain: fold log2(e) into the 1/sqrt(dk) scale
    const float QSC = 0.125f * 1.44269504088896f;

    Epi eQKV = {};   // self Q/K/V fused, N=1536 -> q16|k16|v16
    eQKV.outB[0] = q16; eQKV.outB[1] = k16; eQKV.outB[2] = v16;
    eQKV.bias[0] = sa_bq; eQKV.bias[1] = sa_bk; eQKV.bias[2] = sa_bv;
    eQKV.scale[0] = QSC; eQKV.scale[1] = 1.0f; eQKV.scale[2] = 1.0f;
    eQKV.shift = 9;

    Epi eX1 = {};    // cross1 Q|K|V fused, N=1536; A=y16 (slab0), A2=x116 (slabs 1-2)
    eX1.outB[0] = q16; eX1.outB[1] = k16; eX1.outB[2] = v16;
    eX1.bias[0] = mha_in_b; eX1.bias[1] = mha_in_b + DMODEL; eX1.bias[2] = mha_in_b + 2 * DMODEL;
    eX1.scale[0] = QSC; eX1.scale[1] = 1.0f; eX1.scale[2] = 1.0f;
    eX1.A2 = x116; eX1.a2slab = 1; eX1.shift = 9;

    Epi eX2 = eX1;   // cross2: A=ya16, A2=x216
    eX2.A2 = x216;

    Epi eOut = {};   // out-proj, N=512 -> tmp (fp32)
    eOut.outF[0] = tmp; eOut.bias[0] = mha_out_b; eOut.scale[0] = 1.0f; eOut.shift = 9;

    Epi eF1 = {};    // FFN1, N=2048 -> h16, relu
    eF1.outB[0] = h16; eF1.bias[0] = ffn_b1; eF1.scale[0] = 1.0f;
    eF1.shift = 11; eF1.relu = 1;

    Epi eF2 = {};    // FFN2, N=512 -> tmp (fp32)
    eF2.outF[0] = tmp; eF2.bias[0] = ffn_b2; eF2.scale[0] = 1.0f; eF2.shift = 9;

    // ---- self attention (causal, no out-proj) ----
    gemm2<64, 64><<<dim3(64, 24), blk, 0, stream>>>(xq16, w_sa_qkv, eQKV, DMODEL);
    attn_mfma<<<agrid, ablk, 0, stream>>>(q16, k16, v16, tmp, nullptr, 1);
    ln_kernel<<<NROWS, blk, 0, stream>>>(tmp, x_q, nullptr, ln1_g, ln1_b, nullptr, y16);

    // ---- cross attention 1: q from y, k/v from x1 (one fused GEMM) ----
    gemm2<64, 64><<<dim3(64, 24), blk, 0, stream>>>(y16, w_in, eX1, DMODEL);
    attn_mfma<<<agrid, ablk, 0, stream>>>(q16, k16, v16, nullptr, a16, 0);
    gemm2<64, 64><<<dim3(64, 8), blk, 0, stream>>>(a16, w_out, eOut, DMODEL);
    ln_kernel<<<NROWS, blk, 0, stream>>>(tmp, nullptr, y16, ln2_g, ln2_b, nullptr, ya16);

    // ---- cross attention 2: q from yattn, k/v from x2 ----
    gemm2<64, 64><<<dim3(64, 24), blk, 0, stream>>>(ya16, w_in, eX2, DMODEL);
    attn_mfma<<<agrid, ablk, 0, stream>>>(q16, k16, v16, nullptr, a16, 0);
    gemm2<64, 64><<<dim3(64, 8), blk, 0, stream>>>(a16, w_out, eOut, DMODEL);
    ln_kernel<<<NROWS, blk, 0, stream>>>(tmp, nullptr, ya16, ln2_g, ln2_b, nullptr, ya2);

    // ---- FFN ----
    gemm2<128, 128><<<dim3(32, 16), blk, 0, stream>>>(ya2, w_f1, eF1, DMODEL);
    gemm2<64, 64><<<dim3(64, 8), blk, 0, stream>>>(h16, w_f2, eF2, FFDIM);
    ln_kernel<<<NROWS, blk, 0, stream>>>(tmp, nullptr, ya2, ln3_g, ln3_b, (float*)d_out, nullptr);
}

// Round 8
// 464.135 us; speedup vs baseline: 1.3367x; 1.3367x over previous
//
#include <hip/hip_runtime.h>
#include <hip/hip_bf16.h>

#define S_LEN 2048
#define DMODEL 512
#define NHEAD 8
#define DKH 64
#define FFDIM 2048
#define BATCH 2
#define NROWS (BATCH * S_LEN)  // 4096

using bf16 = __hip_bfloat16;
typedef __bf16 bf16x8 __attribute__((ext_vector_type(8)));
typedef float floatx4 __attribute__((ext_vector_type(4)));
typedef float floatx16 __attribute__((ext_vector_type(16)));

// fp32 -> bf16 round-to-nearest-even, branch-free (scalar path, cvt kernel)
__device__ inline unsigned short f2bf_bits(float f) {
    union { float f; unsigned u; } c; c.f = f;
    return (unsigned short)((c.u + 0x7FFFu + ((c.u >> 16) & 1u)) >> 16);
}
__device__ inline unsigned pack2bf(float a, float b) {
    return (unsigned)f2bf_bits(a) | ((unsigned)f2bf_bits(b) << 16);
}
// packed conversion (v_cvt_pk_bf16_f32 on gfx950)
__device__ inline unsigned pk2(float a, float b) {
    float2 f; f.x = a; f.y = b;
    __hip_bfloat162 h = __float22bfloat162_rn(f);
    return *(unsigned*)&h;
}

// async global->LDS, 16 bytes/lane. LDS dest is wave-uniform base + lane*16.
__device__ __forceinline__ void gload_lds16(const bf16* g, bf16* l) {
    __builtin_amdgcn_global_load_lds(
        (const __attribute__((address_space(1))) void*)(const void*)g,
        (__attribute__((address_space(3))) void*)(void*)l, 16, 0, 0);
}

// ---------------------------------------------------------------------------
// fp32 -> bf16 bulk convert, up to 12 segments in one dispatch.
// ---------------------------------------------------------------------------
struct CvtSeg { const float* s; bf16* d; int n4; };
struct CvtDesc { CvtSeg seg[12]; };

__launch_bounds__(256)
__global__ void cvt_f32_bf16(CvtDesc desc) {
    const CvtSeg sg = desc.seg[blockIdx.y];
    const int stride = gridDim.x * 256;
    for (int i = blockIdx.x * 256 + threadIdx.x; i < sg.n4; i += stride) {
        const float4 v = ((const float4*)sg.s)[i];
        uint2 o;
        o.x = pack2bf(v.x, v.y);
        o.y = pack2bf(v.z, v.w);
        ((uint2*)sg.d)[i] = o;
    }
}

// ---------------------------------------------------------------------------
// GEMM v2: C[M,N] = A[M,K] @ W[N,K]^T, BK=64 as two BK=32 panels. Epilogue
// routes 2^shift-wide column slabs to up to 3 outputs with per-slab bias/
// scale; A2 (if set) replaces A for slabs >= a2slab (fused cross Q|K|V with
// different activation sources). 4 waves (2x2), one barrier pair per 64-k.
// ---------------------------------------------------------------------------
struct Epi {
    bf16*  outB[3];
    float* outF[3];
    const float* bias[3];
    float scale[3];
    const bf16* A2;   // alternate A source for slabs >= a2slab (or null)
    int a2slab;
    int shift;        // log2(slab width): 9 for 512-wide outputs, 11 for FFN1
    int relu;
};

template <int BM, int BN>
__launch_bounds__(256)
__global__ void gemm2(const bf16* __restrict__ A, const bf16* __restrict__ W,
                      Epi epi, int K)
{
    constexpr int WR = BM / 32;
    constexpr int WC = BN / 32;
    constexpr int SA = BM / 16;          // A gload segments per panel
    constexpr int SB = BN / 16;
    constexpr int NG = 2 * (SA + SB);    // gloads per iter (1KB each)

    __shared__ alignas(16) bf16 As[2][BM][32];
    __shared__ alignas(16) bf16 Bs[2][BN][32];

    const int t = threadIdx.x;
    const int w = t >> 6;
    const int lane = t & 63;
    const int r16 = lane & 15;
    const int quad = lane >> 4;
    const int wm = w >> 1, wn = w & 1;
    const int m0 = blockIdx.x * BM;
    const int n0 = blockIdx.y * BN;

    const bf16* Ause = (epi.A2 && ((n0 >> epi.shift) >= epi.a2slab)) ? epi.A2 : A;

    floatx4 acc[WR][WC];
#pragma unroll
    for (int i = 0; i < WR; i++)
#pragma unroll
        for (int j = 0; j < WC; j++)
#pragma unroll
            for (int e = 0; e < 4; e++) acc[i][j][e] = 0.0f;

    const int grow = lane >> 2;        // row within 16-row gload segment
    const int gcol = (lane & 3) * 8;   // k-offset within 32-panel

    for (int k0 = 0; k0 < K; k0 += 64) {
        __syncthreads();
#pragma unroll
        for (int s = 0; s < NG; s += 4) {
            int sg = s + w;
            int p = 0;
            if (sg >= SA + SB) { p = 1; sg -= SA + SB; }
            const bf16* src;
            bf16* dst;
            if (sg < SA) {
                src = Ause + (size_t)(m0 + sg * 16 + grow) * K + k0 + 32 * p + gcol;
                dst = &As[p][sg * 16][0] + lane * 8;
            } else {
                const int sb = sg - SA;
                src = W + (size_t)(n0 + sb * 16 + grow) * K + k0 + 32 * p + gcol;
                dst = &Bs[p][sb * 16][0] + lane * 8;
            }
            gload_lds16(src, dst);
        }
        __syncthreads();

        bf16x8 af[2][WR], bfr[2][WC];
#pragma unroll
        for (int p = 0; p < 2; p++) {
#pragma unroll
            for (int i = 0; i < WR; i++)
                af[p][i] = *(const bf16x8*)&As[p][wm * (BM / 2) + 16 * i + r16][quad * 8];
#pragma unroll
            for (int j = 0; j < WC; j++)
                bfr[p][j] = *(const bf16x8*)&Bs[p][wn * (BN / 2) + 16 * j + r16][quad * 8];
        }
#pragma unroll
        for (int p = 0; p < 2; p++)
#pragma unroll
            for (int i = 0; i < WR; i++)
#pragma unroll
                for (int j = 0; j < WC; j++)
                    acc[i][j] = __builtin_amdgcn_mfma_f32_16x16x32_bf16(af[p][i], bfr[p][j], acc[i][j], 0, 0, 0);
    }

    const int mask = (1 << epi.shift) - 1;
#pragma unroll
    for (int j = 0; j < WC; j++) {
        const int colb = n0 + wn * (BN / 2) + 16 * j;
        const int sel = __builtin_amdgcn_readfirstlane(colb >> epi.shift);
        const int lcol = (colb & mask) + r16;
        const int ldw = mask + 1;
        const float bv = epi.bias[sel] ? epi.bias[sel][lcol] : 0.0f;
        const float sc = epi.scale[sel];
        bf16* ob = epi.outB[sel];
        float* of = epi.outF[sel];
#pragma unroll
        for (int i = 0; i < WR; i++) {
            const int rowb = m0 + wm * (BM / 2) + 16 * i + 4 * quad;
#pragma unroll
            for (int e = 0; e < 4; e++) {
                float v = (acc[i][j][e] + bv) * sc;
                if (epi.relu) v = fmaxf(v, 0.0f);
                const size_t idx = (size_t)(rowb + e) * ldw + lcol;
                if (of) of[idx] = v;
                if (ob) ob[idx] = __float2bfloat16(v);
            }
        }
    }
}

// ---------------------------------------------------------------------------
// Flash attention, 32x32x16 MFMA — round-17 == round-16 resubmission (the
// r7 bench died on container infrastructure, not the kernel).
// r6 post-mortem: OccupancyPercent doubled to 36.9% (occupancy design
// worked) but __launch_bounds__(256,4) imposed a 64-VGPR cap (empirical
// rule across r1/r3/r6: cap = 256/arg2, independent of block size) ->
// 378 MB scratch spill -> 131 us. This round: (256,2) -> 128-VGPR cap;
// body (~100-120 VGPR) fits, and 128 still allows 4 waves/SIMD so the
// LDS-limited 4 blocks/CU x 4 waves = 16 waves/CU residency is preserved.
// Structure (round-15): QBLK=32, 4 waves, grid 64x16=1024 blocks, 36.9KB
// LDS, zero K-loop barriers (per-wave V half-plane + per-wave Ps plane),
// coalesced V staging, K frags from global, exp2 softmax, defer-max,
// setprio, 3-barrier tree merge at the end.
// ---------------------------------------------------------------------------
#define PST 72    // Ps row stride (bf16)
#define PSTH 36   // V half-plane row stride (bf16): 32 + 4

__launch_bounds__(256, 2)
__global__ void attn_mfma(const bf16* __restrict__ Qh, const bf16* __restrict__ Kh,
                          const bf16* __restrict__ Vh,
                          float* __restrict__ outF, bf16* __restrict__ outB,
                          int causal)
{
    // [0,18432):     Vt[4][64][PSTH] bf16 (per-wave V half-planes, d-major)
    // [18432,36864): Ps[4][32][PST]  bf16 (per-wave P planes)
    // after loop: Msh[2][64][34] fp32 (17408 B) overlays [0,18432)+
    __shared__ alignas(16) char smem[36864];
    typedef bf16 (*VtT)[64][PSTH];
    typedef bf16 (*PsT)[32][PST];
    VtT Vt = (VtT)smem;
    PsT Ps = (PsT)(smem + 18432);
    typedef float (*MshT)[64][34];
    MshT Msh = (MshT)smem;

    const int t = threadIdx.x;        // 0..255
    const int w = t >> 6;             // 0..3 (= key-split index)
    const int lane = t & 63;
    const int c32 = lane & 31;
    const int hi = lane >> 5;
    const int bh = blockIdx.y;
    const int b = bh >> 3, h = bh & 7;
    const int q0 = blockIdx.x * 32;
    const size_t rowbase = (size_t)b * S_LEN;
    const int hoff = h * DKH;

    // Q fragments (same 32 q-rows for all 4 waves)
    bf16x8 qf[4];
    {
        const bf16* qp = Qh + (rowbase + q0 + c32) * DMODEL + hoff + 8 * hi;
#pragma unroll
        for (int tt = 0; tt < 4; tt++) qf[tt] = *(const bf16x8*)(qp + 16 * tt);
    }

    floatx16 o0, o1;
#pragma unroll
    for (int e = 0; e < 16; e++) { o0[e] = 0.0f; o1[e] = 0.0f; }
    float m = -3e38f, l = 0.0f;

    // V staging lane map: 8 lanes of d-slices x 8 row-quads -> 100% line use
    const int vq = lane & 7;          // row-quad: rows 4vq..4vq+3 of the half
    const int vd = (lane >> 3) * 8;   // d-slice 0..56

    const int nchunk = causal ? (q0 / 64 + 1) : (S_LEN / 64);

    // K fragments for this wave's first chunk
    bf16x8 kf0[4], kf1[4];
    if (w < nchunk) {
        const bf16* kp = Kh + (rowbase + w * 64 + c32) * DMODEL + hoff + 8 * hi;
#pragma unroll
        for (int tt = 0; tt < 4; tt++) {
            kf0[tt] = *(const bf16x8*)(kp + 16 * tt);
            kf1[tt] = *(const bf16x8*)(kp + (size_t)32 * DMODEL + 16 * tt);
        }
    }

    for (int ch = w; ch < nchunk; ch += 4) {
        const int kb = ch * 64;

        // ---- QK^T ----
        floatx16 s0, s1;
#pragma unroll
        for (int e = 0; e < 16; e++) { s0[e] = 0.0f; s1[e] = 0.0f; }
        __builtin_amdgcn_s_setprio(1);
#pragma unroll
        for (int tt = 0; tt < 4; tt++) {
            s0 = __builtin_amdgcn_mfma_f32_32x32x16_bf16(kf0[tt], qf[tt], s0, 0, 0, 0);
            s1 = __builtin_amdgcn_mfma_f32_32x32x16_bf16(kf1[tt], qf[tt], s1, 0, 0, 0);
        }
        __builtin_amdgcn_s_setprio(0);

        // ---- issue V half0 loads (rows kb..kb+31), coalesced 128B rows ----
        const bf16* vb0 = Vh + (rowbase + kb + 4 * vq) * DMODEL + hoff + vd;
        uint4 va0 = *(const uint4*)(vb0);
        uint4 va1 = *(const uint4*)(vb0 + DMODEL);
        uint4 va2 = *(const uint4*)(vb0 + 2 * DMODEL);
        uint4 va3 = *(const uint4*)(vb0 + 3 * DMODEL);

        // ---- causal mask (diagonal chunk only) ----
        if (causal && ch == nchunk - 1) {
            const int qq = q0 + c32;
#pragma unroll
            for (int r = 0; r < 16; r++) {
                const int kl = kb + (r & 3) + 8 * (r >> 2) + 4 * hi;
                if (kl > qq) s0[r] = -3e38f;
                if (kl + 32 > qq) s1[r] = -3e38f;
            }
        }

        // ---- online softmax (exp2 domain, defer-max) ----
        float mc = -3e38f;
#pragma unroll
        for (int r = 0; r < 16; r++) mc = fmaxf(mc, fmaxf(s0[r], s1[r]));
        mc = fmaxf(mc, __shfl_xor(mc, 32, 64));

        float alpha = 1.0f;
        if (!__all(mc <= m + 8.0f)) {
            const float mold = m;
            m = fmaxf(m, mc);
            alpha = __builtin_amdgcn_exp2f(mold - m);
#pragma unroll
            for (int r = 0; r < 16; r++) {
                const float a = __shfl(alpha, (r & 3) + 8 * (r >> 2) + 4 * hi, 64);
                o0[r] *= a; o1[r] *= a;
            }
        }

        float lc = 0.0f;
#pragma unroll
        for (int g = 0; g < 4; g++) {
            float p0 = __builtin_amdgcn_exp2f(s0[4 * g + 0] - m);
            float p1 = __builtin_amdgcn_exp2f(s0[4 * g + 1] - m);
            float p2 = __builtin_amdgcn_exp2f(s0[4 * g + 2] - m);
            float p3 = __builtin_amdgcn_exp2f(s0[4 * g + 3] - m);
            lc += (p0 + p1) + (p2 + p3);
            uint2 pw; pw.x = pk2(p0, p1); pw.y = pk2(p2, p3);
            *(uint2*)&Ps[w][c32][8 * g + 4 * hi] = pw;
            p0 = __builtin_amdgcn_exp2f(s1[4 * g + 0] - m);
            p1 = __builtin_amdgcn_exp2f(s1[4 * g + 1] - m);
            p2 = __builtin_amdgcn_exp2f(s1[4 * g + 2] - m);
            p3 = __builtin_amdgcn_exp2f(s1[4 * g + 3] - m);
            lc += (p0 + p1) + (p2 + p3);
            uint2 pw1; pw1.x = pk2(p0, p1); pw1.y = pk2(p2, p3);
            *(uint2*)&Ps[w][c32][32 + 8 * g + 4 * hi] = pw1;
        }
        lc += __shfl_xor(lc, 32, 64);
        l = l * alpha + lc;

        // ---- prefetch next chunk's K fragments (hidden under PV) ----
        if (ch + 4 < nchunk) {
            const bf16* kp = Kh + (rowbase + (ch + 4) * 64 + c32) * DMODEL + hoff + 8 * hi;
#pragma unroll
            for (int tt = 0; tt < 4; tt++) {
                kf0[tt] = *(const bf16x8*)(kp + 16 * tt);
                kf1[tt] = *(const bf16x8*)(kp + (size_t)32 * DMODEL + 16 * tt);
            }
        }

        // ---- write V half0 transposed into per-wave plane ----
        {
            union { uint4 u; unsigned short s[8]; } r0, r1, r2, r3;
            r0.u = va0; r1.u = va1; r2.u = va2; r3.u = va3;
#pragma unroll
            for (int j = 0; j < 8; j++) {
                ushort4 pk = { r0.s[j], r1.s[j], r2.s[j], r3.s[j] };
                *(ushort4*)&Vt[w][vd + j][4 * vq] = pk;
            }
        }

        // ---- issue V half1 loads (rows kb+32..kb+63) ----
        const bf16* vb1 = Vh + (rowbase + kb + 32 + 4 * vq) * DMODEL + hoff + vd;
        uint4 vc0 = *(const uint4*)(vb1);
        uint4 vc1 = *(const uint4*)(vb1 + DMODEL);
        uint4 vc2 = *(const uint4*)(vb1 + 2 * DMODEL);
        uint4 vc3 = *(const uint4*)(vb1 + 3 * DMODEL);

        // ---- PV half0 (keys kb..kb+31): pf tiles 0,1 ----
        __builtin_amdgcn_s_setprio(1);
#pragma unroll
        for (int tt = 0; tt < 2; tt++) {
            const bf16x8 pf = *(const bf16x8*)&Ps[w][c32][16 * tt + 8 * hi];
            const bf16x8 v0 = *(const bf16x8*)&Vt[w][c32][16 * tt + 8 * hi];
            const bf16x8 v1 = *(const bf16x8*)&Vt[w][32 + c32][16 * tt + 8 * hi];
            o0 = __builtin_amdgcn_mfma_f32_32x32x16_bf16(pf, v0, o0, 0, 0, 0);
            o1 = __builtin_amdgcn_mfma_f32_32x32x16_bf16(pf, v1, o1, 0, 0, 0);
        }
        __builtin_amdgcn_s_setprio(0);

        // ---- write V half1 (per-wave DS is in-order: reads above complete
        //      before these writes land) ----
        {
            union { uint4 u; unsigned short s[8]; } r0, r1, r2, r3;
            r0.u = vc0; r1.u = vc1; r2.u = vc2; r3.u = vc3;
#pragma unroll
            for (int j = 0; j < 8; j++) {
                ushort4 pk = { r0.s[j], r1.s[j], r2.s[j], r3.s[j] };
                *(ushort4*)&Vt[w][vd + j][4 * vq] = pk;
            }
        }

        // ---- PV half1 (keys kb+32..kb+63): pf tiles 2,3 ----
        __builtin_amdgcn_s_setprio(1);
#pragma unroll
        for (int tt = 2; tt < 4; tt++) {
            const bf16x8 pf = *(const bf16x8*)&Ps[w][c32][16 * tt + 8 * hi];
            const bf16x8 v0 = *(const bf16x8*)&Vt[w][c32][16 * (tt - 2) + 8 * hi];
            const bf16x8 v1 = *(const bf16x8*)&Vt[w][32 + c32][16 * (tt - 2) + 8 * hi];
            o0 = __builtin_amdgcn_mfma_f32_32x32x16_bf16(pf, v0, o0, 0, 0, 0);
            o1 = __builtin_amdgcn_mfma_f32_32x32x16_bf16(pf, v1, o1, 0, 0, 0);
        }
        __builtin_amdgcn_s_setprio(0);
    }

    // ---- 4-way split-KV tree merge across waves (overlay dead LDS) ----
    __syncthreads();   // all loop DS ops drained -> safe to overlay
    if (w & 1) {       // waves 1,3 -> slots 0,1
        float* dst = &Msh[w >> 1][lane][0];
        dst[0] = m; dst[1] = l;
#pragma unroll
        for (int r = 0; r < 16; r++) { dst[2 + r] = o0[r]; dst[18 + r] = o1[r]; }
    }
    __syncthreads();
    if ((w & 1) == 0) {   // waves 0,2 combine (un-normalized)
        const float* src = &Msh[w >> 1][lane][0];
        const float m_b = src[0], l_b = src[1];
        const float mt = fmaxf(m, m_b);
        const float sA = __builtin_amdgcn_exp2f(m - mt);
        const float sB = __builtin_amdgcn_exp2f(m_b - mt);
        l = l * sA + l_b * sB;
        m = mt;
#pragma unroll
        for (int r = 0; r < 16; r++) {
            const int ql = (r & 3) + 8 * (r >> 2) + 4 * hi;
            const float sAr = __shfl(sA, ql, 64);
            const float sBr = __shfl(sB, ql, 64);
            o0[r] = o0[r] * sAr + src[2 + r] * sBr;
            o1[r] = o1[r] * sAr + src[18 + r] * sBr;
        }
        if (w == 2) {     // wave2 re-publishes its combined state to slot 1
            float* dst = &Msh[1][lane][0];
            dst[0] = m; dst[1] = l;
#pragma unroll
            for (int r = 0; r < 16; r++) { dst[2 + r] = o0[r]; dst[18 + r] = o1[r]; }
        }
    }
    __syncthreads();
    if (w == 0) {
        const float* src = &Msh[1][lane][0];
        const float m_b = src[0], l_b = src[1];
        const float mt = fmaxf(m, m_b);
        const float sA = __builtin_amdgcn_exp2f(m - mt);
        const float sB = __builtin_amdgcn_exp2f(m_b - mt);
        const float lt = l * sA + l_b * sB;
#pragma unroll
        for (int r = 0; r < 16; r++) {
            const int ql = (r & 3) + 8 * (r >> 2) + 4 * hi;
            const float sAr = __shfl(sA, ql, 64);
            const float sBr = __shfl(sB, ql, 64);
            const float li = 1.0f / __shfl(lt, ql, 64);
            const float v0 = (o0[r] * sAr + src[2 + r] * sBr) * li;
            const float v1 = (o1[r] * sAr + src[18 + r] * sBr) * li;
            const size_t idx = (rowbase + q0 + ql) * DMODEL + hoff + c32;
            if (outF) { outF[idx] = v0; outF[idx + 32] = v1; }
            if (outB) { outB[idx] = __float2bfloat16(v0); outB[idx + 32] = __float2bfloat16(v1); }
        }
    }
}

// ---------------------------------------------------------------------------
// Fused residual + LayerNorm over D=512. One WG (256 thr) per row.
// ---------------------------------------------------------------------------
__launch_bounds__(256)
__global__ void ln_kernel(const float* __restrict__ xmain,
                          const float* __restrict__ resF, const bf16* __restrict__ resB,
                          const float* __restrict__ g, const float* __restrict__ bb,
                          float* __restrict__ outF, bf16* __restrict__ outB)
{
    const int row = blockIdx.x;
    const int t = threadIdx.x;
    const size_t base = (size_t)row * DMODEL;

    float x0 = xmain[base + t];
    float x1 = xmain[base + t + 256];
    if (resF) { x0 += resF[base + t]; x1 += resF[base + t + 256]; }
    if (resB) { x0 += __bfloat162float(resB[base + t]); x1 += __bfloat162float(resB[base + t + 256]); }

    __shared__ float sred[4];
    float s = x0 + x1;
#pragma unroll
    for (int off = 32; off > 0; off >>= 1) s += __shfl_down(s, off);
    if ((t & 63) == 0) sred[t >> 6] = s;
    __syncthreads();
    const float mu = (sred[0] + sred[1] + sred[2] + sred[3]) * (1.0f / DMODEL);

    const float d0 = x0 - mu, d1 = x1 - mu;
    float sv = d0 * d0 + d1 * d1;
#pragma unroll
    for (int off = 32; off > 0; off >>= 1) sv += __shfl_down(sv, off);
    __syncthreads();
    if ((t & 63) == 0) sred[t >> 6] = sv;
    __syncthreads();
    const float var = (sred[0] + sred[1] + sred[2] + sred[3]) * (1.0f / DMODEL);
    const float rstd = rsqrtf(var + 1e-5f);

    const float y0 = d0 * rstd * g[t] + bb[t];
    const float y1 = d1 * rstd * g[t + 256] + bb[t + 256];
    if (outF) { outF[base + t] = y0; outF[base + t + 256] = y1; }
    if (outB) { outB[base + t] = __float2bfloat16(y0); outB[base + t + 256] = __float2bfloat16(y1); }
}

// ---------------------------------------------------------------------------
// Workspace layout (55.5 MB) — see round 5 comment.
// ---------------------------------------------------------------------------
extern "C" void kernel_launch(void* const* d_in, const int* in_sizes, int n_in,
                              void* d_out, int out_size, void* d_ws, size_t ws_size,
                              hipStream_t stream)
{
    const float* x_q       = (const float*)d_in[0];
    const float* x1        = (const float*)d_in[1];
    const float* x2        = (const float*)d_in[2];
    const float* sa_wq     = (const float*)d_in[3];
    const float* sa_bq     = (const float*)d_in[4];
    const float* sa_wk     = (const float*)d_in[5];
    const float* sa_bk     = (const float*)d_in[6];
    const float* sa_wv     = (const float*)d_in[7];
    const float* sa_bv     = (const float*)d_in[8];
    const float* ln1_g     = (const float*)d_in[9];
    const float* ln1_b     = (const float*)d_in[10];
    const float* mha_in_w  = (const float*)d_in[11];
    const float* mha_in_b  = (const float*)d_in[12];
    const float* mha_out_w = (const float*)d_in[13];
    const float* mha_out_b = (const float*)d_in[14];
    const float* ln2_g     = (const float*)d_in[15];
    const float* ln2_b     = (const float*)d_in[16];
    const float* ffn_w1    = (const float*)d_in[17];
    const float* ffn_b1    = (const float*)d_in[18];
    const float* ffn_w2    = (const float*)d_in[19];
    const float* ffn_b2    = (const float*)d_in[20];
    const float* ln3_g     = (const float*)d_in[21];
    const float* ln3_b     = (const float*)d_in[22];

    char* ws = (char*)d_ws;
    const size_t MB = 1024 * 1024;
    const size_t KB = 1024;
    bf16*  q16  = (bf16*)(ws + 0 * MB);
    bf16*  k16  = (bf16*)(ws + 4 * MB);
    bf16*  v16  = (bf16*)(ws + 8 * MB);
    bf16*  a16  = (bf16*)(ws + 12 * MB);
    float* tmp  = (float*)(ws + 16 * MB);
    bf16*  y16  = (bf16*)(ws + 24 * MB);
    bf16*  ya16 = (bf16*)(ws + 28 * MB);
    bf16*  ya2  = (bf16*)(ws + 32 * MB);
    bf16*  xq16 = (bf16*)(ws + 36 * MB);
    bf16*  x116 = (bf16*)(ws + 40 * MB);
    bf16*  x216 = (bf16*)(ws + 44 * MB);
    bf16*  w_sa_qkv = (bf16*)(ws + 48 * MB);            // 1.5 MB (3D x D contig)
    bf16*  w_in   = (bf16*)(ws + 49 * MB + 512 * KB);   // 1.5 MB
    bf16*  w_out  = (bf16*)(ws + 51 * MB);              // 0.5 MB
    bf16*  w_f1   = (bf16*)(ws + 51 * MB + 512 * KB);   // 2 MB
    bf16*  w_f2   = (bf16*)(ws + 53 * MB + 512 * KB);   // 2 MB
    bf16*  h16    = (bf16*)(ws + 0 * MB);               // aliases q..a (dead by FFN)

    const int DD = DMODEL * DMODEL;
    CvtDesc cd;
    cd.seg[0]  = { x_q,       xq16,        (NROWS * DMODEL) / 4 };
    cd.seg[1]  = { x1,        x116,        (NROWS * DMODEL) / 4 };
    cd.seg[2]  = { x2,        x216,        (NROWS * DMODEL) / 4 };
    cd.seg[3]  = { sa_wq,     w_sa_qkv,           DD / 4 };
    cd.seg[4]  = { sa_wk,     w_sa_qkv + DD,      DD / 4 };
    cd.seg[5]  = { sa_wv,     w_sa_qkv + 2 * DD,  DD / 4 };
    cd.seg[6]  = { mha_in_w,  w_in,   3 * DD / 4 };
    cd.seg[7]  = { mha_out_w, w_out,  DD / 4 };
    cd.seg[8]  = { ffn_w1,    w_f1,   (FFDIM * DMODEL) / 4 };
    cd.seg[9]  = { ffn_w2,    w_f2,   (FFDIM * DMODEL) / 4 };
    cd.seg[10] = { x_q,       xq16,   0 };
    cd.seg[11] = { x_q,       xq16,   0 };
    cvt_f32_bf16<<<dim3(64, 10), 256, 0, stream>>>(cd);

    const dim3 blk(256);
    const dim3 ablk(256);
    const dim3 agrid(S_LEN / 32, BATCH * NHEAD);   // (64,16) = 1024 blocks

    // softmax runs in exp2 domain: fold log2(e) into the 1/sqrt(dk) scale
    const float QSC = 0.125f * 1.44269504088896f;

    Epi eQKV = {};   // self Q/K/V fused, N=1536 -> q16|k16|v16
    eQKV.outB[0] = q16; eQKV.outB[1] = k16; eQKV.outB[2] = v16;
    eQKV.bias[0] = sa_bq; eQKV.bias[1] = sa_bk; eQKV.bias[2] = sa_bv;
    eQKV.scale[0] = QSC; eQKV.scale[1] = 1.0f; eQKV.scale[2] = 1.0f;
    eQKV.shift = 9;

    Epi eX1 = {};    // cross1 Q|K|V fused, N=1536; A=y16 (slab0), A2=x116 (slabs 1-2)
    eX1.outB[0] = q16; eX1.outB[1] = k16; eX1.outB[2] = v16;
    eX1.bias[0] = mha_in_b; eX1.bias[1] = mha_in_b + DMODEL; eX1.bias[2] = mha_in_b + 2 * DMODEL;
    eX1.scale[0] = QSC; eX1.scale[1] = 1.0f; eX1.scale[2] = 1.0f;
    eX1.A2 = x116; eX1.a2slab = 1; eX1.shift = 9;

    Epi eX2 = eX1;   // cross2: A=ya16, A2=x216
    eX2.A2 = x216;

    Epi eOut = {};   // out-proj, N=512 -> tmp (fp32)
    eOut.outF[0] = tmp; eOut.bias[0] = mha_out_b; eOut.scale[0] = 1.0f; eOut.shift = 9;

    Epi eF1 = {};    // FFN1, N=2048 -> h16, relu
    eF1.outB[0] = h16; eF1.bias[0] = ffn_b1; eF1.scale[0] = 1.0f;
    eF1.shift = 11; eF1.relu = 1;

    Epi eF2 = {};    // FFN2, N=512 -> tmp (fp32)
    eF2.outF[0] = tmp; eF2.bias[0] = ffn_b2; eF2.scale[0] = 1.0f; eF2.shift = 9;

    // ---- self attention (causal, no out-proj) ----
    gemm2<64, 64><<<dim3(64, 24), blk, 0, stream>>>(xq16, w_sa_qkv, eQKV, DMODEL);
    attn_mfma<<<agrid, ablk, 0, stream>>>(q16, k16, v16, tmp, nullptr, 1);
    ln_kernel<<<NROWS, blk, 0, stream>>>(tmp, x_q, nullptr, ln1_g, ln1_b, nullptr, y16);

    // ---- cross attention 1: q from y, k/v from x1 (one fused GEMM) ----
    gemm2<64, 64><<<dim3(64, 24), blk, 0, stream>>>(y16, w_in, eX1, DMODEL);
    attn_mfma<<<agrid, ablk, 0, stream>>>(q16, k16, v16, nullptr, a16, 0);
    gemm2<64, 64><<<dim3(64, 8), blk, 0, stream>>>(a16, w_out, eOut, DMODEL);
    ln_kernel<<<NROWS, blk, 0, stream>>>(tmp, nullptr, y16, ln2_g, ln2_b, nullptr, ya16);

    // ---- cross attention 2: q from yattn, k/v from x2 ----
    gemm2<64, 64><<<dim3(64, 24), blk, 0, stream>>>(ya16, w_in, eX2, DMODEL);
    attn_mfma<<<agrid, ablk, 0, stream>>>(q16, k16, v16, nullptr, a16, 0);
    gemm2<64, 64><<<dim3(64, 8), blk, 0, stream>>>(a16, w_out, eOut, DMODEL);
    ln_kernel<<<NROWS, blk, 0, stream>>>(tmp, nullptr, ya16, ln2_g, ln2_b, nullptr, ya2);

    // ---- FFN ----
    gemm2<128, 128><<<dim3(32, 16), blk, 0, stream>>>(ya2, w_f1, eF1, DMODEL);
    gemm2<64, 64><<<dim3(64, 8), blk, 0, stream>>>(h16, w_f2, eF2, FFDIM);
    ln_kernel<<<NROWS, blk, 0, stream>>>(tmp, nullptr, ya2, ln3_g, ln3_b, (float*)d_out, nullptr);
}

// Round 9
// 443.073 us; speedup vs baseline: 1.4003x; 1.0475x over previous
//
#include <hip/hip_runtime.h>
#include <hip/hip_bf16.h>

#define S_LEN 2048
#define DMODEL 512
#define NHEAD 8
#define DKH 64
#define FFDIM 2048
#define BATCH 2
#define NROWS (BATCH * S_LEN)  // 4096

using bf16 = __hip_bfloat16;
typedef __bf16 bf16x8 __attribute__((ext_vector_type(8)));
typedef float floatx4 __attribute__((ext_vector_type(4)));
typedef float floatx16 __attribute__((ext_vector_type(16)));

// fp32 -> bf16 round-to-nearest-even, branch-free (scalar path, cvt kernel)
__device__ inline unsigned short f2bf_bits(float f) {
    union { float f; unsigned u; } c; c.f = f;
    return (unsigned short)((c.u + 0x7FFFu + ((c.u >> 16) & 1u)) >> 16);
}
__device__ inline unsigned pack2bf(float a, float b) {
    return (unsigned)f2bf_bits(a) | ((unsigned)f2bf_bits(b) << 16);
}
// packed conversion (v_cvt_pk_bf16_f32 on gfx950)
__device__ inline unsigned pk2(float a, float b) {
    float2 f; f.x = a; f.y = b;
    __hip_bfloat162 h = __float22bfloat162_rn(f);
    return *(unsigned*)&h;
}

// async global->LDS, 16 bytes/lane. LDS dest is wave-uniform base + lane*16.
__device__ __forceinline__ void gload_lds16(const bf16* g, bf16* l) {
    __builtin_amdgcn_global_load_lds(
        (const __attribute__((address_space(1))) void*)(const void*)g,
        (__attribute__((address_space(3))) void*)(void*)l, 16, 0, 0);
}

// ---------------------------------------------------------------------------
// fp32 -> bf16 bulk convert, up to 12 segments in one dispatch.
// ---------------------------------------------------------------------------
struct CvtSeg { const float* s; bf16* d; int n4; };
struct CvtDesc { CvtSeg seg[12]; };

__launch_bounds__(256)
__global__ void cvt_f32_bf16(CvtDesc desc) {
    const CvtSeg sg = desc.seg[blockIdx.y];
    const int stride = gridDim.x * 256;
    for (int i = blockIdx.x * 256 + threadIdx.x; i < sg.n4; i += stride) {
        const float4 v = ((const float4*)sg.s)[i];
        uint2 o;
        o.x = pack2bf(v.x, v.y);
        o.y = pack2bf(v.z, v.w);
        ((uint2*)sg.d)[i] = o;
    }
}

// ---------------------------------------------------------------------------
// GEMM v2: C[M,N] = A[M,K] @ W[N,K]^T, BK=64 as two BK=32 panels. Epilogue
// routes 2^shift-wide column slabs to up to 3 outputs with per-slab bias/
// scale; A2 (if set) replaces A for slabs >= a2slab (fused cross Q|K|V with
// different activation sources). 4 waves (2x2), one barrier pair per 64-k.
// ---------------------------------------------------------------------------
struct Epi {
    bf16*  outB[3];
    float* outF[3];
    const float* bias[3];
    float scale[3];
    const bf16* A2;   // alternate A source for slabs >= a2slab (or null)
    int a2slab;
    int shift;        // log2(slab width): 9 for 512-wide outputs, 11 for FFN1
    int relu;
};

template <int BM, int BN>
__launch_bounds__(256)
__global__ void gemm2(const bf16* __restrict__ A, const bf16* __restrict__ W,
                      Epi epi, int K)
{
    constexpr int WR = BM / 32;
    constexpr int WC = BN / 32;
    constexpr int SA = BM / 16;          // A gload segments per panel
    constexpr int SB = BN / 16;
    constexpr int NG = 2 * (SA + SB);    // gloads per iter (1KB each)

    __shared__ alignas(16) bf16 As[2][BM][32];
    __shared__ alignas(16) bf16 Bs[2][BN][32];

    const int t = threadIdx.x;
    const int w = t >> 6;
    const int lane = t & 63;
    const int r16 = lane & 15;
    const int quad = lane >> 4;
    const int wm = w >> 1, wn = w & 1;
    const int m0 = blockIdx.x * BM;
    const int n0 = blockIdx.y * BN;

    const bf16* Ause = (epi.A2 && ((n0 >> epi.shift) >= epi.a2slab)) ? epi.A2 : A;

    floatx4 acc[WR][WC];
#pragma unroll
    for (int i = 0; i < WR; i++)
#pragma unroll
        for (int j = 0; j < WC; j++)
#pragma unroll
            for (int e = 0; e < 4; e++) acc[i][j][e] = 0.0f;

    const int grow = lane >> 2;        // row within 16-row gload segment
    const int gcol = (lane & 3) * 8;   // k-offset within 32-panel

    for (int k0 = 0; k0 < K; k0 += 64) {
        __syncthreads();
#pragma unroll
        for (int s = 0; s < NG; s += 4) {
            int sg = s + w;
            int p = 0;
            if (sg >= SA + SB) { p = 1; sg -= SA + SB; }
            const bf16* src;
            bf16* dst;
            if (sg < SA) {
                src = Ause + (size_t)(m0 + sg * 16 + grow) * K + k0 + 32 * p + gcol;
                dst = &As[p][sg * 16][0] + lane * 8;
            } else {
                const int sb = sg - SA;
                src = W + (size_t)(n0 + sb * 16 + grow) * K + k0 + 32 * p + gcol;
                dst = &Bs[p][sb * 16][0] + lane * 8;
            }
            gload_lds16(src, dst);
        }
        __syncthreads();

        bf16x8 af[2][WR], bfr[2][WC];
#pragma unroll
        for (int p = 0; p < 2; p++) {
#pragma unroll
            for (int i = 0; i < WR; i++)
                af[p][i] = *(const bf16x8*)&As[p][wm * (BM / 2) + 16 * i + r16][quad * 8];
#pragma unroll
            for (int j = 0; j < WC; j++)
                bfr[p][j] = *(const bf16x8*)&Bs[p][wn * (BN / 2) + 16 * j + r16][quad * 8];
        }
#pragma unroll
        for (int p = 0; p < 2; p++)
#pragma unroll
            for (int i = 0; i < WR; i++)
#pragma unroll
                for (int j = 0; j < WC; j++)
                    acc[i][j] = __builtin_amdgcn_mfma_f32_16x16x32_bf16(af[p][i], bfr[p][j], acc[i][j], 0, 0, 0);
    }

    const int mask = (1 << epi.shift) - 1;
#pragma unroll
    for (int j = 0; j < WC; j++) {
        const int colb = n0 + wn * (BN / 2) + 16 * j;
        const int sel = __builtin_amdgcn_readfirstlane(colb >> epi.shift);
        const int lcol = (colb & mask) + r16;
        const int ldw = mask + 1;
        const float bv = epi.bias[sel] ? epi.bias[sel][lcol] : 0.0f;
        const float sc = epi.scale[sel];
        bf16* ob = epi.outB[sel];
        float* of = epi.outF[sel];
#pragma unroll
        for (int i = 0; i < WR; i++) {
            const int rowb = m0 + wm * (BM / 2) + 16 * i + 4 * quad;
#pragma unroll
            for (int e = 0; e < 4; e++) {
                float v = (acc[i][j][e] + bv) * sc;
                if (epi.relu) v = fmaxf(v, 0.0f);
                const size_t idx = (size_t)(rowb + e) * ldw + lcol;
                if (of) of[idx] = v;
                if (ob) ob[idx] = __float2bfloat16(v);
            }
        }
    }
}

// ---------------------------------------------------------------------------
// Flash attention, 32x32x16 MFMA — round-18: L2-TRAFFIC.
// r0-r8 post-mortem: attn pinned 65-77us across every structural variant
// (barriers, occupancy, coalescing). The invariant is TOTAL L2 TRAFFIC:
// K/V were fetched per-wave per-q-block from global/L2 (K at 25% line
// efficiency, 4x amplification) ~= 1.3 GB/dispatch -> 50-70us at scattered
// L2 rates. This round: classic flash blocking. QBLK=128, 8 waves (512thr)
// = 4 q-groups x 2 key-halves. Per 64-key chunk, K (8KB) + V (8KB) staged
// ONCE per block, cooperatively, 100% coalesced; all 8 waves consume from
// shared LDS. Traffic -> 16 qblocks x 32 chunks x 16KB x 16bh ~= 131 MB
// (8-10x less). Per-wave tile: 32q x 32k, one floatx16 score reg, 4 QK +
// 4 PV MFMA per chunk. Fragment lane-maps identical to the passing r8
// kernel (kh-offset added). LDS 40KB (Ks[64][72] + Vt[64][72] +
// Ps[8][32][44]); merge scratch overlays after loop. 2 barriers/chunk
// (stage protection); 2-way split-K (kh) merge. launch_bounds(512,2) ->
// 128-VGPR cap (empirical 256/arg2), body peaks ~100.
// ---------------------------------------------------------------------------
#define KST 72    // Ks/Vt row stride (bf16)
#define PST2 44   // Ps row stride (bf16)

__launch_bounds__(512, 2)
__global__ void attn_mfma(const bf16* __restrict__ Qh, const bf16* __restrict__ Kh,
                          const bf16* __restrict__ Vh,
                          float* __restrict__ outF, bf16* __restrict__ outB,
                          int causal)
{
    // [0,9216):      Ks[64][72] bf16 (shared K chunk, row-major)
    // [9216,18432):  Vt[64][72] bf16 (shared V chunk, d-major/transposed)
    // [18432,40960): Ps[8][32][44] bf16 (per-wave P planes)
    // after loop: Msh[4][64][34] fp32 (34816 B) overlays [0,40960)
    __shared__ alignas(16) char smem[40960];
    typedef bf16 (*KsT)[KST];
    KsT Ks = (KsT)smem;
    KsT Vt = (KsT)(smem + 9216);
    typedef bf16 (*PsT)[32][PST2];
    PsT Ps = (PsT)(smem + 18432);
    typedef float (*MshT)[64][34];
    MshT Msh = (MshT)smem;

    const int t = threadIdx.x;        // 0..511
    const int w = t >> 6;             // 0..7
    const int lane = t & 63;
    const int c32 = lane & 31;
    const int hi = lane >> 5;
    const int qg = w >> 1;            // 0..3 q-group (32 rows each)
    const int kh = w & 1;             // 0..1 key-half (32 keys each)
    const int bh = blockIdx.y;
    const int b = bh >> 3, h = bh & 7;
    const int q0 = blockIdx.x * 128;
    const size_t rowbase = (size_t)b * S_LEN;
    const int hoff = h * DKH;

    // Q fragments: rows q0 + qg*32 + c32 (once per block; uncoalesced ok)
    bf16x8 qf[4];
    {
        const bf16* qp = Qh + (rowbase + q0 + qg * 32 + c32) * DMODEL + hoff + 8 * hi;
#pragma unroll
        for (int tt = 0; tt < 4; tt++) qf[tt] = *(const bf16x8*)(qp + 16 * tt);
    }

    floatx16 o0, o1;
#pragma unroll
    for (int e = 0; e < 16; e++) { o0[e] = 0.0f; o1[e] = 0.0f; }
    float m = -3e38f, l = 0.0f;

    // stage maps
    const int krow = t >> 3;            // t<256: K rows krow and krow+32
    const int kcol = (t & 7) * 8;       // 8 threads cover a full 128B row
    const int pl = t - 256;             // t in [256,384): V stagers
    const int rq = pl & 15;             // row-quad (4 rows)
    const int c8 = ((pl >> 4) & 7) * 8; // d-slice

    const int nchunk = causal ? (q0 / 64 + 2) : (S_LEN / 64);

    for (int ch = 0; ch < nchunk; ch++) {
        const int kb = ch * 64;
        __syncthreads();   // all reads of previous chunk's Ks/Vt drained

        if (t < 256) {
            // stage K chunk (coalesced; 2 rows per thread)
            const bf16* kp = Kh + (rowbase + kb + krow) * DMODEL + hoff + kcol;
            uint4 ka = *(const uint4*)(kp);
            uint4 kc = *(const uint4*)(kp + (size_t)32 * DMODEL);
            *(uint4*)&Ks[krow][kcol] = ka;
            *(uint4*)&Ks[krow + 32][kcol] = kc;
        } else if (t < 384) {
            // stage V transposed (coalesced reads; packed b64 writes)
            union { uint4 u; unsigned short s[8]; } r0, r1, r2, r3;
            const bf16* vb = Vh + (rowbase + kb + 4 * rq) * DMODEL + hoff + c8;
            r0.u = *(const uint4*)(vb);
            r1.u = *(const uint4*)(vb + DMODEL);
            r2.u = *(const uint4*)(vb + 2 * DMODEL);
            r3.u = *(const uint4*)(vb + 3 * DMODEL);
#pragma unroll
            for (int j = 0; j < 8; j++) {
                ushort4 pk = { r0.s[j], r1.s[j], r2.s[j], r3.s[j] };
                *(ushort4*)&Vt[c8 + j][4 * rq] = pk;
            }
        }

        __syncthreads();   // staged chunk visible to all waves

        // ---- QK^T: this wave's 32q x 32k ----
        bf16x8 kf[4];
#pragma unroll
        for (int tt = 0; tt < 4; tt++)
            kf[tt] = *(const bf16x8*)&Ks[kh * 32 + c32][16 * tt + 8 * hi];

        floatx16 s;
#pragma unroll
        for (int e = 0; e < 16; e++) s[e] = 0.0f;
        __builtin_amdgcn_s_setprio(1);
#pragma unroll
        for (int tt = 0; tt < 4; tt++)
            s = __builtin_amdgcn_mfma_f32_32x32x16_bf16(kf[tt], qf[tt], s, 0, 0, 0);
        __builtin_amdgcn_s_setprio(0);

        // ---- causal mask (last two chunks only) ----
        if (causal && ch >= nchunk - 2) {
            const int qq = q0 + qg * 32 + c32;
#pragma unroll
            for (int r = 0; r < 16; r++) {
                const int kl = kb + kh * 32 + (r & 3) + 8 * (r >> 2) + 4 * hi;
                if (kl > qq) s[r] = -3e38f;
            }
        }

        // ---- online softmax (exp2 domain, defer-max) over 32 keys ----
        float mc = -3e38f;
#pragma unroll
        for (int r = 0; r < 16; r++) mc = fmaxf(mc, s[r]);
        mc = fmaxf(mc, __shfl_xor(mc, 32, 64));

        float alpha = 1.0f;
        if (!__all(mc <= m + 8.0f)) {
            const float mold = m;
            m = fmaxf(m, mc);
            alpha = __builtin_amdgcn_exp2f(mold - m);
#pragma unroll
            for (int r = 0; r < 16; r++) {
                const float a = __shfl(alpha, (r & 3) + 8 * (r >> 2) + 4 * hi, 64);
                o0[r] *= a; o1[r] *= a;
            }
        }

        float lc = 0.0f;
#pragma unroll
        for (int g = 0; g < 4; g++) {
            float p0 = __builtin_amdgcn_exp2f(s[4 * g + 0] - m);
            float p1 = __builtin_amdgcn_exp2f(s[4 * g + 1] - m);
            float p2 = __builtin_amdgcn_exp2f(s[4 * g + 2] - m);
            float p3 = __builtin_amdgcn_exp2f(s[4 * g + 3] - m);
            lc += (p0 + p1) + (p2 + p3);
            uint2 pw; pw.x = pk2(p0, p1); pw.y = pk2(p2, p3);
            *(uint2*)&Ps[w][c32][8 * g + 4 * hi] = pw;
        }
        lc += __shfl_xor(lc, 32, 64);
        l = l * alpha + lc;

        // ---- PV: o(32q x 64d) partial over this key-half ----
        __builtin_amdgcn_s_setprio(1);
#pragma unroll
        for (int tt = 0; tt < 2; tt++) {
            const bf16x8 pf = *(const bf16x8*)&Ps[w][c32][16 * tt + 8 * hi];
            const bf16x8 v0 = *(const bf16x8*)&Vt[c32][kh * 32 + 16 * tt + 8 * hi];
            const bf16x8 v1 = *(const bf16x8*)&Vt[32 + c32][kh * 32 + 16 * tt + 8 * hi];
            o0 = __builtin_amdgcn_mfma_f32_32x32x16_bf16(pf, v0, o0, 0, 0, 0);
            o1 = __builtin_amdgcn_mfma_f32_32x32x16_bf16(pf, v1, o1, 0, 0, 0);
        }
        __builtin_amdgcn_s_setprio(0);
    }

    // ---- 2-way split-K merge across kh waves (overlay dead LDS) ----
    __syncthreads();   // all loop LDS reads drained -> safe to overlay
    if (kh == 1) {
        float* dst = &Msh[qg][lane][0];
        dst[0] = m; dst[1] = l;
#pragma unroll
        for (int r = 0; r < 16; r++) { dst[2 + r] = o0[r]; dst[18 + r] = o1[r]; }
    }
    __syncthreads();
    if (kh == 0) {
        const float* src = &Msh[qg][lane][0];
        const float m_b = src[0], l_b = src[1];
        const float mt = fmaxf(m, m_b);
        const float sA = __builtin_amdgcn_exp2f(m - mt);
        const float sB = __builtin_amdgcn_exp2f(m_b - mt);
        const float lt = l * sA + l_b * sB;
#pragma unroll
        for (int r = 0; r < 16; r++) {
            const int ql = (r & 3) + 8 * (r >> 2) + 4 * hi;
            const float sAr = __shfl(sA, ql, 64);
            const float sBr = __shfl(sB, ql, 64);
            const float li = 1.0f / __shfl(lt, ql, 64);
            const float v0 = (o0[r] * sAr + src[2 + r] * sBr) * li;
            const float v1 = (o1[r] * sAr + src[18 + r] * sBr) * li;
            const size_t idx = (rowbase + q0 + qg * 32 + ql) * DMODEL + hoff + c32;
            if (outF) { outF[idx] = v0; outF[idx + 32] = v1; }
            if (outB) { outB[idx] = __float2bfloat16(v0); outB[idx + 32] = __float2bfloat16(v1); }
        }
    }
}

// ---------------------------------------------------------------------------
// Fused residual + LayerNorm over D=512. One WG (256 thr) per row.
// ---------------------------------------------------------------------------
__launch_bounds__(256)
__global__ void ln_kernel(const float* __restrict__ xmain,
                          const float* __restrict__ resF, const bf16* __restrict__ resB,
                          const float* __restrict__ g, const float* __restrict__ bb,
                          float* __restrict__ outF, bf16* __restrict__ outB)
{
    const int row = blockIdx.x;
    const int t = threadIdx.x;
    const size_t base = (size_t)row * DMODEL;

    float x0 = xmain[base + t];
    float x1 = xmain[base + t + 256];
    if (resF) { x0 += resF[base + t]; x1 += resF[base + t + 256]; }
    if (resB) { x0 += __bfloat162float(resB[base + t]); x1 += __bfloat162float(resB[base + t + 256]); }

    __shared__ float sred[4];
    float s = x0 + x1;
#pragma unroll
    for (int off = 32; off > 0; off >>= 1) s += __shfl_down(s, off);
    if ((t & 63) == 0) sred[t >> 6] = s;
    __syncthreads();
    const float mu = (sred[0] + sred[1] + sred[2] + sred[3]) * (1.0f / DMODEL);

    const float d0 = x0 - mu, d1 = x1 - mu;
    float sv = d0 * d0 + d1 * d1;
#pragma unroll
    for (int off = 32; off > 0; off >>= 1) sv += __shfl_down(sv, off);
    __syncthreads();
    if ((t & 63) == 0) sred[t >> 6] = sv;
    __syncthreads();
    const float var = (sred[0] + sred[1] + sred[2] + sred[3]) * (1.0f / DMODEL);
    const float rstd = rsqrtf(var + 1e-5f);

    const float y0 = d0 * rstd * g[t] + bb[t];
    const float y1 = d1 * rstd * g[t + 256] + bb[t + 256];
    if (outF) { outF[base + t] = y0; outF[base + t + 256] = y1; }
    if (outB) { outB[base + t] = __float2bfloat16(y0); outB[base + t + 256] = __float2bfloat16(y1); }
}

// ---------------------------------------------------------------------------
// Workspace layout (55.5 MB) — see round 5 comment.
// ---------------------------------------------------------------------------
extern "C" void kernel_launch(void* const* d_in, const int* in_sizes, int n_in,
                              void* d_out, int out_size, void* d_ws, size_t ws_size,
                              hipStream_t stream)
{
    const float* x_q       = (const float*)d_in[0];
    const float* x1        = (const float*)d_in[1];
    const float* x2        = (const float*)d_in[2];
    const float* sa_wq     = (const float*)d_in[3];
    const float* sa_bq     = (const float*)d_in[4];
    const float* sa_wk     = (const float*)d_in[5];
    const float* sa_bk     = (const float*)d_in[6];
    const float* sa_wv     = (const float*)d_in[7];
    const float* sa_bv     = (const float*)d_in[8];
    const float* ln1_g     = (const float*)d_in[9];
    const float* ln1_b     = (const float*)d_in[10];
    const float* mha_in_w  = (const float*)d_in[11];
    const float* mha_in_b  = (const float*)d_in[12];
    const float* mha_out_w = (const float*)d_in[13];
    const float* mha_out_b = (const float*)d_in[14];
    const float* ln2_g     = (const float*)d_in[15];
    const float* ln2_b     = (const float*)d_in[16];
    const float* ffn_w1    = (const float*)d_in[17];
    const float* ffn_b1    = (const float*)d_in[18];
    const float* ffn_w2    = (const float*)d_in[19];
    const float* ffn_b2    = (const float*)d_in[20];
    const float* ln3_g     = (const float*)d_in[21];
    const float* ln3_b     = (const float*)d_in[22];

    char* ws = (char*)d_ws;
    const size_t MB = 1024 * 1024;
    const size_t KB = 1024;
    bf16*  q16  = (bf16*)(ws + 0 * MB);
    bf16*  k16  = (bf16*)(ws + 4 * MB);
    bf16*  v16  = (bf16*)(ws + 8 * MB);
    bf16*  a16  = (bf16*)(ws + 12 * MB);
    float* tmp  = (float*)(ws + 16 * MB);
    bf16*  y16  = (bf16*)(ws + 24 * MB);
    bf16*  ya16 = (bf16*)(ws + 28 * MB);
    bf16*  ya2  = (bf16*)(ws + 32 * MB);
    bf16*  xq16 = (bf16*)(ws + 36 * MB);
    bf16*  x116 = (bf16*)(ws + 40 * MB);
    bf16*  x216 = (bf16*)(ws + 44 * MB);
    bf16*  w_sa_qkv = (bf16*)(ws + 48 * MB);            // 1.5 MB (3D x D contig)
    bf16*  w_in   = (bf16*)(ws + 49 * MB + 512 * KB);   // 1.5 MB
    bf16*  w_out  = (bf16*)(ws + 51 * MB);              // 0.5 MB
    bf16*  w_f1   = (bf16*)(ws + 51 * MB + 512 * KB);   // 2 MB
    bf16*  w_f2   = (bf16*)(ws + 53 * MB + 512 * KB);   // 2 MB
    bf16*  h16    = (bf16*)(ws + 0 * MB);               // aliases q..a (dead by FFN)

    const int DD = DMODEL * DMODEL;
    CvtDesc cd;
    cd.seg[0]  = { x_q,       xq16,        (NROWS * DMODEL) / 4 };
    cd.seg[1]  = { x1,        x116,        (NROWS * DMODEL) / 4 };
    cd.seg[2]  = { x2,        x216,        (NROWS * DMODEL) / 4 };
    cd.seg[3]  = { sa_wq,     w_sa_qkv,           DD / 4 };
    cd.seg[4]  = { sa_wk,     w_sa_qkv + DD,      DD / 4 };
    cd.seg[5]  = { sa_wv,     w_sa_qkv + 2 * DD,  DD / 4 };
    cd.seg[6]  = { mha_in_w,  w_in,   3 * DD / 4 };
    cd.seg[7]  = { mha_out_w, w_out,  DD / 4 };
    cd.seg[8]  = { ffn_w1,    w_f1,   (FFDIM * DMODEL) / 4 };
    cd.seg[9]  = { ffn_w2,    w_f2,   (FFDIM * DMODEL) / 4 };
    cd.seg[10] = { x_q,       xq16,   0 };
    cd.seg[11] = { x_q,       xq16,   0 };
    cvt_f32_bf16<<<dim3(64, 10), 256, 0, stream>>>(cd);

    const dim3 blk(256);
    const dim3 ablk(512);
    const dim3 agrid(S_LEN / 128, BATCH * NHEAD);   // (16,16) = 256 blocks

    // softmax runs in exp2 domain: fold log2(e) into the 1/sqrt(dk) scale
    const float QSC = 0.125f * 1.44269504088896f;

    Epi eQKV = {};   // self Q/K/V fused, N=1536 -> q16|k16|v16
    eQKV.outB[0] = q16; eQKV.outB[1] = k16; eQKV.outB[2] = v16;
    eQKV.bias[0] = sa_bq; eQKV.bias[1] = sa_bk; eQKV.bias[2] = sa_bv;
    eQKV.scale[0] = QSC; eQKV.scale[1] = 1.0f; eQKV.scale[2] = 1.0f;
    eQKV.shift = 9;

    Epi eX1 = {};    // cross1 Q|K|V fused, N=1536; A=y16 (slab0), A2=x116 (slabs 1-2)
    eX1.outB[0] = q16; eX1.outB[1] = k16; eX1.outB[2] = v16;
    eX1.bias[0] = mha_in_b; eX1.bias[1] = mha_in_b + DMODEL; eX1.bias[2] = mha_in_b + 2 * DMODEL;
    eX1.scale[0] = QSC; eX1.scale[1] = 1.0f; eX1.scale[2] = 1.0f;
    eX1.A2 = x116; eX1.a2slab = 1; eX1.shift = 9;

    Epi eX2 = eX1;   // cross2: A=ya16, A2=x216
    eX2.A2 = x216;

    Epi eOut = {};   // out-proj, N=512 -> tmp (fp32)
    eOut.outF[0] = tmp; eOut.bias[0] = mha_out_b; eOut.scale[0] = 1.0f; eOut.shift = 9;

    Epi eF1 = {};    // FFN1, N=2048 -> h16, relu
    eF1.outB[0] = h16; eF1.bias[0] = ffn_b1; eF1.scale[0] = 1.0f;
    eF1.shift = 11; eF1.relu = 1;

    Epi eF2 = {};    // FFN2, N=512 -> tmp (fp32)
    eF2.outF[0] = tmp; eF2.bias[0] = ffn_b2; eF2.scale[0] = 1.0f; eF2.shift = 9;

    // ---- self attention (causal, no out-proj) ----
    gemm2<64, 64><<<dim3(64, 24), blk, 0, stream>>>(xq16, w_sa_qkv, eQKV, DMODEL);
    attn_mfma<<<agrid, ablk, 0, stream>>>(q16, k16, v16, tmp, nullptr, 1);
    ln_kernel<<<NROWS, blk, 0, stream>>>(tmp, x_q, nullptr, ln1_g, ln1_b, nullptr, y16);

    // ---- cross attention 1: q from y, k/v from x1 (one fused GEMM) ----
    gemm2<64, 64><<<dim3(64, 24), blk, 0, stream>>>(y16, w_in, eX1, DMODEL);
    attn_mfma<<<agrid, ablk, 0, stream>>>(q16, k16, v16, nullptr, a16, 0);
    gemm2<64, 64><<<dim3(64, 8), blk, 0, stream>>>(a16, w_out, eOut, DMODEL);
    ln_kernel<<<NROWS, blk, 0, stream>>>(tmp, nullptr, y16, ln2_g, ln2_b, nullptr, ya16);

    // ---- cross attention 2: q from yattn, k/v from x2 ----
    gemm2<64, 64><<<dim3(64, 24), blk, 0, stream>>>(ya16, w_in, eX2, DMODEL);
    attn_mfma<<<agrid, ablk, 0, stream>>>(q16, k16, v16, nullptr, a16, 0);
    gemm2<64, 64><<<dim3(64, 8), blk, 0, stream>>>(a16, w_out, eOut, DMODEL);
    ln_kernel<<<NROWS, blk, 0, stream>>>(tmp, nullptr, ya16, ln2_g, ln2_b, nullptr, ya2);

    // ---- FFN ----
    gemm2<128, 128><<<dim3(32, 16), blk, 0, stream>>>(ya2, w_f1, eF1, DMODEL);
    gemm2<64, 64><<<dim3(64, 8), blk, 0, stream>>>(h16, w_f2, eF2, FFDIM);
    ln_kernel<<<NROWS, blk, 0, stream>>>(tmp, nullptr, ya2, ln3_g, ln3_b, (float*)d_out, nullptr);
}

// Round 10
// 409.618 us; speedup vs baseline: 1.5146x; 1.0817x over previous
//
#include <hip/hip_runtime.h>
#include <hip/hip_bf16.h>

#define S_LEN 2048
#define DMODEL 512
#define NHEAD 8
#define DKH 64
#define FFDIM 2048
#define BATCH 2
#define NROWS (BATCH * S_LEN)  // 4096

using bf16 = __hip_bfloat16;
typedef __bf16 bf16x8 __attribute__((ext_vector_type(8)));
typedef float floatx4 __attribute__((ext_vector_type(4)));
typedef float floatx16 __attribute__((ext_vector_type(16)));

// fp32 -> bf16 round-to-nearest-even, branch-free (scalar path, cvt kernel)
__device__ inline unsigned short f2bf_bits(float f) {
    union { float f; unsigned u; } c; c.f = f;
    return (unsigned short)((c.u + 0x7FFFu + ((c.u >> 16) & 1u)) >> 16);
}
__device__ inline unsigned pack2bf(float a, float b) {
    return (unsigned)f2bf_bits(a) | ((unsigned)f2bf_bits(b) << 16);
}
// packed conversion (v_cvt_pk_bf16_f32 on gfx950)
__device__ inline unsigned pk2(float a, float b) {
    float2 f; f.x = a; f.y = b;
    __hip_bfloat162 h = __float22bfloat162_rn(f);
    return *(unsigned*)&h;
}

// async global->LDS, 16 bytes/lane. LDS dest is wave-uniform base + lane*16.
__device__ __forceinline__ void gload_lds16(const bf16* g, bf16* l) {
    __builtin_amdgcn_global_load_lds(
        (const __attribute__((address_space(1))) void*)(const void*)g,
        (__attribute__((address_space(3))) void*)(void*)l, 16, 0, 0);
}

// ---------------------------------------------------------------------------
// fp32 -> bf16 bulk convert, up to 12 segments in one dispatch.
// ---------------------------------------------------------------------------
struct CvtSeg { const float* s; bf16* d; int n4; };
struct CvtDesc { CvtSeg seg[12]; };

__launch_bounds__(256)
__global__ void cvt_f32_bf16(CvtDesc desc) {
    const CvtSeg sg = desc.seg[blockIdx.y];
    const int stride = gridDim.x * 256;
    for (int i = blockIdx.x * 256 + threadIdx.x; i < sg.n4; i += stride) {
        const float4 v = ((const float4*)sg.s)[i];
        uint2 o;
        o.x = pack2bf(v.x, v.y);
        o.y = pack2bf(v.z, v.w);
        ((uint2*)sg.d)[i] = o;
    }
}

// ---------------------------------------------------------------------------
// GEMM v2: C[M,N] = A[M,K] @ W[N,K]^T, BK=64 as two BK=32 panels. Epilogue
// routes 2^shift-wide column slabs to up to 3 outputs with per-slab bias/
// scale; A2 (if set) replaces A for slabs >= a2slab (fused cross Q|K|V with
// different activation sources). 4 waves (2x2), one barrier pair per 64-k.
// ---------------------------------------------------------------------------
struct Epi {
    bf16*  outB[3];
    float* outF[3];
    const float* bias[3];
    float scale[3];
    const bf16* A2;   // alternate A source for slabs >= a2slab (or null)
    int a2slab;
    int shift;        // log2(slab width): 9 for 512-wide outputs, 11 for FFN1
    int relu;
};

template <int BM, int BN>
__launch_bounds__(256)
__global__ void gemm2(const bf16* __restrict__ A, const bf16* __restrict__ W,
                      Epi epi, int K)
{
    constexpr int WR = BM / 32;
    constexpr int WC = BN / 32;
    constexpr int SA = BM / 16;          // A gload segments per panel
    constexpr int SB = BN / 16;
    constexpr int NG = 2 * (SA + SB);    // gloads per iter (1KB each)

    __shared__ alignas(16) bf16 As[2][BM][32];
    __shared__ alignas(16) bf16 Bs[2][BN][32];

    const int t = threadIdx.x;
    const int w = t >> 6;
    const int lane = t & 63;
    const int r16 = lane & 15;
    const int quad = lane >> 4;
    const int wm = w >> 1, wn = w & 1;
    const int m0 = blockIdx.x * BM;
    const int n0 = blockIdx.y * BN;

    const bf16* Ause = (epi.A2 && ((n0 >> epi.shift) >= epi.a2slab)) ? epi.A2 : A;

    floatx4 acc[WR][WC];
#pragma unroll
    for (int i = 0; i < WR; i++)
#pragma unroll
        for (int j = 0; j < WC; j++)
#pragma unroll
            for (int e = 0; e < 4; e++) acc[i][j][e] = 0.0f;

    const int grow = lane >> 2;        // row within 16-row gload segment
    const int gcol = (lane & 3) * 8;   // k-offset within 32-panel

    for (int k0 = 0; k0 < K; k0 += 64) {
        __syncthreads();
#pragma unroll
        for (int s = 0; s < NG; s += 4) {
            int sg = s + w;
            int p = 0;
            if (sg >= SA + SB) { p = 1; sg -= SA + SB; }
            const bf16* src;
            bf16* dst;
            if (sg < SA) {
                src = Ause + (size_t)(m0 + sg * 16 + grow) * K + k0 + 32 * p + gcol;
                dst = &As[p][sg * 16][0] + lane * 8;
            } else {
                const int sb = sg - SA;
                src = W + (size_t)(n0 + sb * 16 + grow) * K + k0 + 32 * p + gcol;
                dst = &Bs[p][sb * 16][0] + lane * 8;
            }
            gload_lds16(src, dst);
        }
        __syncthreads();

        bf16x8 af[2][WR], bfr[2][WC];
#pragma unroll
        for (int p = 0; p < 2; p++) {
#pragma unroll
            for (int i = 0; i < WR; i++)
                af[p][i] = *(const bf16x8*)&As[p][wm * (BM / 2) + 16 * i + r16][quad * 8];
#pragma unroll
            for (int j = 0; j < WC; j++)
                bfr[p][j] = *(const bf16x8*)&Bs[p][wn * (BN / 2) + 16 * j + r16][quad * 8];
        }
#pragma unroll
        for (int p = 0; p < 2; p++)
#pragma unroll
            for (int i = 0; i < WR; i++)
#pragma unroll
                for (int j = 0; j < WC; j++)
                    acc[i][j] = __builtin_amdgcn_mfma_f32_16x16x32_bf16(af[p][i], bfr[p][j], acc[i][j], 0, 0, 0);
    }

    const int mask = (1 << epi.shift) - 1;
#pragma unroll
    for (int j = 0; j < WC; j++) {
        const int colb = n0 + wn * (BN / 2) + 16 * j;
        const int sel = __builtin_amdgcn_readfirstlane(colb >> epi.shift);
        const int lcol = (colb & mask) + r16;
        const int ldw = mask + 1;
        const float bv = epi.bias[sel] ? epi.bias[sel][lcol] : 0.0f;
        const float sc = epi.scale[sel];
        bf16* ob = epi.outB[sel];
        float* of = epi.outF[sel];
#pragma unroll
        for (int i = 0; i < WR; i++) {
            const int rowb = m0 + wm * (BM / 2) + 16 * i + 4 * quad;
#pragma unroll
            for (int e = 0; e < 4; e++) {
                float v = (acc[i][j][e] + bv) * sc;
                if (epi.relu) v = fmaxf(v, 0.0f);
                const size_t idx = (size_t)(rowb + e) * ldw + lcol;
                if (of) of[idx] = v;
                if (ob) ob[idx] = __float2bfloat16(v);
            }
        }
    }
}

// ---------------------------------------------------------------------------
// Flash attention, 32x32x16 MFMA — round-19: ASYNC STAGE (T14) + DOUBLE BUF.
// r0-r9 post-mortem: nine structures all land 63-77us. The one constant:
// the global->LDS fetch of chunk ch was always ON chunk ch's critical path
// (stage -> barrier -> compute) with <=2 waves/SIMD to hide ~300-900cy of
// L2/HBM latency -> 4.7k cyc/chunk observed vs ~700 of real work.
// This round (on the r9 flash-blocked structure):
//  (a) chunk ch+1 is loaded into REGISTERS while chunk ch computes; at the
//      top of iter ch the (arrived) regs are written to LDS buf[ch&1] and
//      loads for ch+2 are issued -> fetch latency hides under a full
//      compute phase.
//  (b) LDS double-buffered (Ks/Vt x2) -> ONE barrier per chunk (write of
//      ch+1 can't race reads of ch).
//  (c) QBLK=64, 4 waves (2 qg x 2 kh), grid 32x16=512 blocks = 2 blocks/CU
//      so a second block overlaps barrier convoys. LDS 47KB.
// Fragment maps / softmax / merge verbatim from the passing r9 kernel.
// launch_bounds(256,2) -> 128-VGPR cap (empirical 256/arg2); body ~110.
// ---------------------------------------------------------------------------
#define KST 72    // Ks/Vt row stride (bf16)
#define PST2 44   // Ps row stride (bf16)

__launch_bounds__(256, 2)
__global__ void attn_mfma(const bf16* __restrict__ Qh, const bf16* __restrict__ Kh,
                          const bf16* __restrict__ Vh,
                          float* __restrict__ outF, bf16* __restrict__ outB,
                          int causal)
{
    // [0,18432):     Ks[2][64][72] bf16 (double-buffered K chunk, row-major)
    // [18432,36864): Vt[2][64][72] bf16 (double-buffered V chunk, d-major)
    // [36864,48128): Ps[4][32][44] bf16 (per-wave P planes)
    // after loop: Msh[2][64][34] fp32 (17408 B) overlays [0,48128)
    __shared__ alignas(16) char smem[48128];
    typedef bf16 (*KbufT)[64][KST];
    KbufT Ks = (KbufT)smem;
    KbufT Vt = (KbufT)(smem + 18432);
    typedef bf16 (*PsT)[32][PST2];
    PsT Ps = (PsT)(smem + 36864);
    typedef float (*MshT)[64][34];
    MshT Msh = (MshT)smem;

    const int t = threadIdx.x;        // 0..255
    const int w = t >> 6;             // 0..3
    const int lane = t & 63;
    const int c32 = lane & 31;
    const int hi = lane >> 5;
    const int qg = w >> 1;            // 0..1 q-group (32 rows each)
    const int kh = w & 1;             // 0..1 key-half (32 keys each)
    const int bh = blockIdx.y;
    const int b = bh >> 3, h = bh & 7;
    const int q0 = blockIdx.x * 64;
    const size_t rowbase = (size_t)b * S_LEN;
    const int hoff = h * DKH;

    // Q fragments: rows q0 + qg*32 + c32
    bf16x8 qf[4];
    {
        const bf16* qp = Qh + (rowbase + q0 + qg * 32 + c32) * DMODEL + hoff + 8 * hi;
#pragma unroll
        for (int tt = 0; tt < 4; tt++) qf[tt] = *(const bf16x8*)(qp + 16 * tt);
    }

    floatx16 o0, o1;
#pragma unroll
    for (int e = 0; e < 16; e++) { o0[e] = 0.0f; o1[e] = 0.0f; }
    float m = -3e38f, l = 0.0f;

    // stage maps
    const int krow = t >> 3;            // K rows krow and krow+32 (all 256 thr)
    const int kcol = (t & 7) * 8;       // 8 threads cover a full 128B row
    const int pl = t & 127;             // V stagers: t >= 128
    const int rq = pl & 15;             // row-quad (4 rows)
    const int c8 = ((pl >> 4) & 7) * 8; // d-slice
    const bool vstager = (t >= 128);

    const int nchunk = causal ? (q0 / 64 + 1) : (S_LEN / 64);

    // ---- prologue: load chunk 0 into registers ----
    uint4 kra, krb, vr0, vr1, vr2, vr3;
    {
        const bf16* kp = Kh + (rowbase + krow) * DMODEL + hoff + kcol;
        kra = *(const uint4*)(kp);
        krb = *(const uint4*)(kp + (size_t)32 * DMODEL);
        if (vstager) {
            const bf16* vb = Vh + (rowbase + 4 * rq) * DMODEL + hoff + c8;
            vr0 = *(const uint4*)(vb);
            vr1 = *(const uint4*)(vb + DMODEL);
            vr2 = *(const uint4*)(vb + 2 * DMODEL);
            vr3 = *(const uint4*)(vb + 3 * DMODEL);
        }
    }

    for (int ch = 0; ch < nchunk; ch++) {
        const int buf = ch & 1;
        const int kb = ch * 64;

        // ---- write staged chunk ch into buf (regs arrived during ch-1) ----
        *(uint4*)&Ks[buf][krow][kcol] = kra;
        *(uint4*)&Ks[buf][krow + 32][kcol] = krb;
        if (vstager) {
            union { uint4 u; unsigned short s[8]; } r0, r1, r2, r3;
            r0.u = vr0; r1.u = vr1; r2.u = vr2; r3.u = vr3;
#pragma unroll
            for (int j = 0; j < 8; j++) {
                ushort4 pk = { r0.s[j], r1.s[j], r2.s[j], r3.s[j] };
                *(ushort4*)&Vt[buf][c8 + j][4 * rq] = pk;
            }
        }

        // ---- issue loads for chunk ch+1 (latency hides under compute) ----
        if (ch + 1 < nchunk) {
            const int kb1 = (ch + 1) * 64;
            const bf16* kp = Kh + (rowbase + kb1 + krow) * DMODEL + hoff + kcol;
            kra = *(const uint4*)(kp);
            krb = *(const uint4*)(kp + (size_t)32 * DMODEL);
            if (vstager) {
                const bf16* vb = Vh + (rowbase + kb1 + 4 * rq) * DMODEL + hoff + c8;
                vr0 = *(const uint4*)(vb);
                vr1 = *(const uint4*)(vb + DMODEL);
                vr2 = *(const uint4*)(vb + 2 * DMODEL);
                vr3 = *(const uint4*)(vb + 3 * DMODEL);
            }
        }

        __syncthreads();   // buf's writes visible; prior reads of buf^1 done

        // ---- QK^T: this wave's 32q x 32k ----
        bf16x8 kf[4];
#pragma unroll
        for (int tt = 0; tt < 4; tt++)
            kf[tt] = *(const bf16x8*)&Ks[buf][kh * 32 + c32][16 * tt + 8 * hi];

        floatx16 s;
#pragma unroll
        for (int e = 0; e < 16; e++) s[e] = 0.0f;
        __builtin_amdgcn_s_setprio(1);
#pragma unroll
        for (int tt = 0; tt < 4; tt++)
            s = __builtin_amdgcn_mfma_f32_32x32x16_bf16(kf[tt], qf[tt], s, 0, 0, 0);
        __builtin_amdgcn_s_setprio(0);

        // ---- causal mask (diagonal chunk only at QBLK=64) ----
        if (causal && ch == nchunk - 1) {
            const int qq = q0 + qg * 32 + c32;
#pragma unroll
            for (int r = 0; r < 16; r++) {
                const int kl = kb + kh * 32 + (r & 3) + 8 * (r >> 2) + 4 * hi;
                if (kl > qq) s[r] = -3e38f;
            }
        }

        // ---- online softmax (exp2 domain, defer-max) over 32 keys ----
        float mc = -3e38f;
#pragma unroll
        for (int r = 0; r < 16; r++) mc = fmaxf(mc, s[r]);
        mc = fmaxf(mc, __shfl_xor(mc, 32, 64));

        float alpha = 1.0f;
        if (!__all(mc <= m + 8.0f)) {
            const float mold = m;
            m = fmaxf(m, mc);
            alpha = __builtin_amdgcn_exp2f(mold - m);
#pragma unroll
            for (int r = 0; r < 16; r++) {
                const float a = __shfl(alpha, (r & 3) + 8 * (r >> 2) + 4 * hi, 64);
                o0[r] *= a; o1[r] *= a;
            }
        }

        float lc = 0.0f;
#pragma unroll
        for (int g = 0; g < 4; g++) {
            float p0 = __builtin_amdgcn_exp2f(s[4 * g + 0] - m);
            float p1 = __builtin_amdgcn_exp2f(s[4 * g + 1] - m);
            float p2 = __builtin_amdgcn_exp2f(s[4 * g + 2] - m);
            float p3 = __builtin_amdgcn_exp2f(s[4 * g + 3] - m);
            lc += (p0 + p1) + (p2 + p3);
            uint2 pw; pw.x = pk2(p0, p1); pw.y = pk2(p2, p3);
            *(uint2*)&Ps[w][c32][8 * g + 4 * hi] = pw;
        }
        lc += __shfl_xor(lc, 32, 64);
        l = l * alpha + lc;

        // ---- PV: o(32q x 64d) partial over this key-half ----
        __builtin_amdgcn_s_setprio(1);
#pragma unroll
        for (int tt = 0; tt < 2; tt++) {
            const bf16x8 pf = *(const bf16x8*)&Ps[w][c32][16 * tt + 8 * hi];
            const bf16x8 v0 = *(const bf16x8*)&Vt[buf][c32][kh * 32 + 16 * tt + 8 * hi];
            const bf16x8 v1 = *(const bf16x8*)&Vt[buf][32 + c32][kh * 32 + 16 * tt + 8 * hi];
            o0 = __builtin_amdgcn_mfma_f32_32x32x16_bf16(pf, v0, o0, 0, 0, 0);
            o1 = __builtin_amdgcn_mfma_f32_32x32x16_bf16(pf, v1, o1, 0, 0, 0);
        }
        __builtin_amdgcn_s_setprio(0);
    }

    // ---- 2-way split-K merge across kh waves (overlay dead LDS) ----
    __syncthreads();   // all loop LDS ops drained -> safe to overlay
    if (kh == 1) {
        float* dst = &Msh[qg][lane][0];
        dst[0] = m; dst[1] = l;
#pragma unroll
        for (int r = 0; r < 16; r++) { dst[2 + r] = o0[r]; dst[18 + r] = o1[r]; }
    }
    __syncthreads();
    if (kh == 0) {
        const float* src = &Msh[qg][lane][0];
        const float m_b = src[0], l_b = src[1];
        const float mt = fmaxf(m, m_b);
        const float sA = __builtin_amdgcn_exp2f(m - mt);
        const float sB = __builtin_amdgcn_exp2f(m_b - mt);
        const float lt = l * sA + l_b * sB;
#pragma unroll
        for (int r = 0; r < 16; r++) {
            const int ql = (r & 3) + 8 * (r >> 2) + 4 * hi;
            const float sAr = __shfl(sA, ql, 64);
            const float sBr = __shfl(sB, ql, 64);
            const float li = 1.0f / __shfl(lt, ql, 64);
            const float v0 = (o0[r] * sAr + src[2 + r] * sBr) * li;
            const float v1 = (o1[r] * sAr + src[18 + r] * sBr) * li;
            const size_t idx = (rowbase + q0 + qg * 32 + ql) * DMODEL + hoff + c32;
            if (outF) { outF[idx] = v0; outF[idx + 32] = v1; }
            if (outB) { outB[idx] = __float2bfloat16(v0); outB[idx + 32] = __float2bfloat16(v1); }
        }
    }
}

// ---------------------------------------------------------------------------
// Fused residual + LayerNorm over D=512. One WG (256 thr) per row.
// ---------------------------------------------------------------------------
__launch_bounds__(256)
__global__ void ln_kernel(const float* __restrict__ xmain,
                          const float* __restrict__ resF, const bf16* __restrict__ resB,
                          const float* __restrict__ g, const float* __restrict__ bb,
                          float* __restrict__ outF, bf16* __restrict__ outB)
{
    const int row = blockIdx.x;
    const int t = threadIdx.x;
    const size_t base = (size_t)row * DMODEL;

    float x0 = xmain[base + t];
    float x1 = xmain[base + t + 256];
    if (resF) { x0 += resF[base + t]; x1 += resF[base + t + 256]; }
    if (resB) { x0 += __bfloat162float(resB[base + t]); x1 += __bfloat162float(resB[base + t + 256]); }

    __shared__ float sred[4];
    float s = x0 + x1;
#pragma unroll
    for (int off = 32; off > 0; off >>= 1) s += __shfl_down(s, off);
    if ((t & 63) == 0) sred[t >> 6] = s;
    __syncthreads();
    const float mu = (sred[0] + sred[1] + sred[2] + sred[3]) * (1.0f / DMODEL);

    const float d0 = x0 - mu, d1 = x1 - mu;
    float sv = d0 * d0 + d1 * d1;
#pragma unroll
    for (int off = 32; off > 0; off >>= 1) sv += __shfl_down(sv, off);
    __syncthreads();
    if ((t & 63) == 0) sred[t >> 6] = sv;
    __syncthreads();
    const float var = (sred[0] + sred[1] + sred[2] + sred[3]) * (1.0f / DMODEL);
    const float rstd = rsqrtf(var + 1e-5f);

    const float y0 = d0 * rstd * g[t] + bb[t];
    const float y1 = d1 * rstd * g[t + 256] + bb[t + 256];
    if (outF) { outF[base + t] = y0; outF[base + t + 256] = y1; }
    if (outB) { outB[base + t] = __float2bfloat16(y0); outB[base + t + 256] = __float2bfloat16(y1); }
}

// ---------------------------------------------------------------------------
// Workspace layout (55.5 MB) — see round 5 comment.
// ---------------------------------------------------------------------------
extern "C" void kernel_launch(void* const* d_in, const int* in_sizes, int n_in,
                              void* d_out, int out_size, void* d_ws, size_t ws_size,
                              hipStream_t stream)
{
    const float* x_q       = (const float*)d_in[0];
    const float* x1        = (const float*)d_in[1];
    const float* x2        = (const float*)d_in[2];
    const float* sa_wq     = (const float*)d_in[3];
    const float* sa_bq     = (const float*)d_in[4];
    const float* sa_wk     = (const float*)d_in[5];
    const float* sa_bk     = (const float*)d_in[6];
    const float* sa_wv     = (const float*)d_in[7];
    const float* sa_bv     = (const float*)d_in[8];
    const float* ln1_g     = (const float*)d_in[9];
    const float* ln1_b     = (const float*)d_in[10];
    const float* mha_in_w  = (const float*)d_in[11];
    const float* mha_in_b  = (const float*)d_in[12];
    const float* mha_out_w = (const float*)d_in[13];
    const float* mha_out_b = (const float*)d_in[14];
    const float* ln2_g     = (const float*)d_in[15];
    const float* ln2_b     = (const float*)d_in[16];
    const float* ffn_w1    = (const float*)d_in[17];
    const float* ffn_b1    = (const float*)d_in[18];
    const float* ffn_w2    = (const float*)d_in[19];
    const float* ffn_b2    = (const float*)d_in[20];
    const float* ln3_g     = (const float*)d_in[21];
    const float* ln3_b     = (const float*)d_in[22];

    char* ws = (char*)d_ws;
    const size_t MB = 1024 * 1024;
    const size_t KB = 1024;
    bf16*  q16  = (bf16*)(ws + 0 * MB);
    bf16*  k16  = (bf16*)(ws + 4 * MB);
    bf16*  v16  = (bf16*)(ws + 8 * MB);
    bf16*  a16  = (bf16*)(ws + 12 * MB);
    float* tmp  = (float*)(ws + 16 * MB);
    bf16*  y16  = (bf16*)(ws + 24 * MB);
    bf16*  ya16 = (bf16*)(ws + 28 * MB);
    bf16*  ya2  = (bf16*)(ws + 32 * MB);
    bf16*  xq16 = (bf16*)(ws + 36 * MB);
    bf16*  x116 = (bf16*)(ws + 40 * MB);
    bf16*  x216 = (bf16*)(ws + 44 * MB);
    bf16*  w_sa_qkv = (bf16*)(ws + 48 * MB);            // 1.5 MB (3D x D contig)
    bf16*  w_in   = (bf16*)(ws + 49 * MB + 512 * KB);   // 1.5 MB
    bf16*  w_out  = (bf16*)(ws + 51 * MB);              // 0.5 MB
    bf16*  w_f1   = (bf16*)(ws + 51 * MB + 512 * KB);   // 2 MB
    bf16*  w_f2   = (bf16*)(ws + 53 * MB + 512 * KB);   // 2 MB
    bf16*  h16    = (bf16*)(ws + 0 * MB);               // aliases q..a (dead by FFN)

    const int DD = DMODEL * DMODEL;
    CvtDesc cd;
    cd.seg[0]  = { x_q,       xq16,        (NROWS * DMODEL) / 4 };
    cd.seg[1]  = { x1,        x116,        (NROWS * DMODEL) / 4 };
    cd.seg[2]  = { x2,        x216,        (NROWS * DMODEL) / 4 };
    cd.seg[3]  = { sa_wq,     w_sa_qkv,           DD / 4 };
    cd.seg[4]  = { sa_wk,     w_sa_qkv + DD,      DD / 4 };
    cd.seg[5]  = { sa_wv,     w_sa_qkv + 2 * DD,  DD / 4 };
    cd.seg[6]  = { mha_in_w,  w_in,   3 * DD / 4 };
    cd.seg[7]  = { mha_out_w, w_out,  DD / 4 };
    cd.seg[8]  = { ffn_w1,    w_f1,   (FFDIM * DMODEL) / 4 };
    cd.seg[9]  = { ffn_w2,    w_f2,   (FFDIM * DMODEL) / 4 };
    cd.seg[10] = { x_q,       xq16,   0 };
    cd.seg[11] = { x_q,       xq16,   0 };
    cvt_f32_bf16<<<dim3(64, 10), 256, 0, stream>>>(cd);

    const dim3 blk(256);
    const dim3 ablk(256);
    const dim3 agrid(S_LEN / 64, BATCH * NHEAD);   // (32,16) = 512 blocks

    // softmax runs in exp2 domain: fold log2(e) into the 1/sqrt(dk) scale
    const float QSC = 0.125f * 1.44269504088896f;

    Epi eQKV = {};   // self Q/K/V fused, N=1536 -> q16|k16|v16
    eQKV.outB[0] = q16; eQKV.outB[1] = k16; eQKV.outB[2] = v16;
    eQKV.bias[0] = sa_bq; eQKV.bias[1] = sa_bk; eQKV.bias[2] = sa_bv;
    eQKV.scale[0] = QSC; eQKV.scale[1] = 1.0f; eQKV.scale[2] = 1.0f;
    eQKV.shift = 9;

    Epi eX1 = {};    // cross1 Q|K|V fused, N=1536; A=y16 (slab0), A2=x116 (slabs 1-2)
    eX1.outB[0] = q16; eX1.outB[1] = k16; eX1.outB[2] = v16;
    eX1.bias[0] = mha_in_b; eX1.bias[1] = mha_in_b + DMODEL; eX1.bias[2] = mha_in_b + 2 * DMODEL;
    eX1.scale[0] = QSC; eX1.scale[1] = 1.0f; eX1.scale[2] = 1.0f;
    eX1.A2 = x116; eX1.a2slab = 1; eX1.shift = 9;

    Epi eX2 = eX1;   // cross2: A=ya16, A2=x216
    eX2.A2 = x216;

    Epi eOut = {};   // out-proj, N=512 -> tmp (fp32)
    eOut.outF[0] = tmp; eOut.bias[0] = mha_out_b; eOut.scale[0] = 1.0f; eOut.shift = 9;

    Epi eF1 = {};    // FFN1, N=2048 -> h16, relu
    eF1.outB[0] = h16; eF1.bias[0] = ffn_b1; eF1.scale[0] = 1.0f;
    eF1.shift = 11; eF1.relu = 1;

    Epi eF2 = {};    // FFN2, N=512 -> tmp (fp32)
    eF2.outF[0] = tmp; eF2.bias[0] = ffn_b2; eF2.scale[0] = 1.0f; eF2.shift = 9;

    // ---- self attention (causal, no out-proj) ----
    gemm2<64, 64><<<dim3(64, 24), blk, 0, stream>>>(xq16, w_sa_qkv, eQKV, DMODEL);
    attn_mfma<<<agrid, ablk, 0, stream>>>(q16, k16, v16, tmp, nullptr, 1);
    ln_kernel<<<NROWS, blk, 0, stream>>>(tmp, x_q, nullptr, ln1_g, ln1_b, nullptr, y16);

    // ---- cross attention 1: q from y, k/v from x1 (one fused GEMM) ----
    gemm2<64, 64><<<dim3(64, 24), blk, 0, stream>>>(y16, w_in, eX1, DMODEL);
    attn_mfma<<<agrid, ablk, 0, stream>>>(q16, k16, v16, nullptr, a16, 0);
    gemm2<64, 64><<<dim3(64, 8), blk, 0, stream>>>(a16, w_out, eOut, DMODEL);
    ln_kernel<<<NROWS, blk, 0, stream>>>(tmp, nullptr, y16, ln2_g, ln2_b, nullptr, ya16);

    // ---- cross attention 2: q from yattn, k/v from x2 ----
    gemm2<64, 64><<<dim3(64, 24), blk, 0, stream>>>(ya16, w_in, eX2, DMODEL);
    attn_mfma<<<agrid, ablk, 0, stream>>>(q16, k16, v16, nullptr, a16, 0);
    gemm2<64, 64><<<dim3(64, 8), blk, 0, stream>>>(a16, w_out, eOut, DMODEL);
    ln_kernel<<<NROWS, blk, 0, stream>>>(tmp, nullptr, ya16, ln2_g, ln2_b, nullptr, ya2);

    // ---- FFN ----
    gemm2<128, 128><<<dim3(32, 16), blk, 0, stream>>>(ya2, w_f1, eF1, DMODEL);
    gemm2<64, 64><<<dim3(64, 8), blk, 0, stream>>>(h16, w_f2, eF2, FFDIM);
    ln_kernel<<<NROWS, blk, 0, stream>>>(tmp, nullptr, ya2, ln3_g, ln3_b, (float*)d_out, nullptr);
}